// Round 5
// baseline (214.401 us; speedup 1.0000x reference)
//
#include <hip/hip_runtime.h>
#include <stdint.h>

#define DEV __device__ __forceinline__

typedef __attribute__((ext_vector_type(8))) unsigned short frag8;    // 8 bf16 = 4 VGPR
typedef __attribute__((ext_vector_type(4))) float f32x4;
typedef __attribute__((ext_vector_type(8))) unsigned short ushort8;
typedef __attribute__((ext_vector_type(4))) unsigned short ushort4v;

DEV unsigned short f2bf(float f) {
  union { float f; unsigned u; } x; x.f = f;
  unsigned r = x.u + 0x7fffu + ((x.u >> 16) & 1u);   // RNE
  return (unsigned short)(r >> 16);
}
DEV float bf2f(unsigned short b) {
  union { unsigned u; float f; } x; x.u = ((unsigned)b) << 16;
  return x.f;
}

DEV void gload_lds16(const void* g, void* l) {
  __builtin_amdgcn_global_load_lds((const __attribute__((address_space(1))) void*)g,
                                   (__attribute__((address_space(3))) void*)l, 16, 0, 0);
}

DEV void mfma_bf16(f32x4& c, frag8 a, frag8 b) {
  asm("v_mfma_f32_16x16x32_bf16 %0, %1, %2, %0" : "+v"(c) : "v"(a), "v"(b));
}

// ---------------------------------------------------------------------------
// C[M,N] = A[M,K]*B[N,K]^T, bf16 in / f32 acc. 128x128 tile, BK=64, 4 waves,
// SINGLE-buffer 32 KiB LDS (round-1 proven: 740 TF, occ 28% — beats the 64 KiB
// dbuf at 640 TF / occ 17.5%). XOR-swizzled LDS via pre-swizzled global source
// (rule #21). 1D grid + bijective XCD swizzle (T1, m204).
// MODE: 0 = bf16 out
//       3 = scores: e = exp((s + c2[bz*N+gc])*scale), bf16 out, rowsum atomics
//       4 = PV: f32 out = acc/rowsum[row] + biasp[gc]
//       5 = fused q'/v': bz==0 plain bf16; bz==1 per-batch transposed store
// ---------------------------------------------------------------------------
template<int MODE>
__global__ __launch_bounds__(256)
void gemm_bt(const unsigned short* __restrict__ A,
             const unsigned short* __restrict__ Bm,
             const float* __restrict__ bias0, const float* __restrict__ bias1,
             float* __restrict__ rowsum,
             void* __restrict__ Cv,
             int N, int K, float scale,
             long sA, long sB, long sC,
             int nx, int ny)
{
  __shared__ unsigned short ldsA[128 * 64];   // 16 KiB
  __shared__ unsigned short ldsB[128 * 64];   // 16 KiB

  const int tid  = threadIdx.x;
  const int lane = tid & 63;
  const int wave = tid >> 6;
  const int wm   = wave >> 1;           // 2x2 waves, 64x64 each
  const int wn   = wave & 1;

  // ---- bijective XCD swizzle (m204) + grid decomposition ----
  const unsigned nwg = gridDim.x;
  const unsigned orig = blockIdx.x;
  const unsigned qq = nwg >> 3, rr = nwg & 7;
  const unsigned xcd = orig & 7, jj = orig >> 3;
  const unsigned wg = (xcd < rr ? xcd * (qq + 1) : rr * (qq + 1) + (xcd - rr) * qq) + jj;
  const unsigned bx = wg % (unsigned)nx;
  const unsigned tt = wg / (unsigned)nx;
  const unsigned by = tt % (unsigned)ny;
  const unsigned bz = tt / (unsigned)ny;

  const int bm = (int)by * 128;
  const int bn = (int)bx * 128;

  A  += (size_t)bz * (size_t)sA;
  Bm += (size_t)bz * (size_t)sB;

  // ---- staging addresses (per wave: 4 instrs of 1KB = 8 rows each side) ----
  const int r8  = lane >> 3;
  const int l8  = lane & 7;
  const int swz = ((l8 ^ r8) << 4);     // pre-swizzled global byte column
  const size_t Kb = (size_t)K * 2;

  const char* gA = (const char*)A  + (size_t)(bm + wave * 32 + r8) * Kb + swz;
  const char* gB = (const char*)Bm + (size_t)(bn + wave * 32 + r8) * Kb + swz;
  char* lA = (char*)ldsA + wave * 32 * 128;
  char* lB = (char*)ldsB + wave * 32 * 128;

  // ---- fragment read addresses ----
  const int cr = lane & 15;
  const int kq = lane >> 4;
  const int base16 = ((kq ^ (cr & 7)) << 4);
  const char* rowA = (const char*)ldsA + (wm * 64 + cr) * 128;
  const char* rowB = (const char*)ldsB + (wn * 64 + cr) * 128;

  f32x4 acc[4][4];
  #pragma unroll
  for (int m = 0; m < 4; ++m)
    #pragma unroll
    for (int n = 0; n < 4; ++n)
      acc[m][n] = f32x4{0.f, 0.f, 0.f, 0.f};

  const int nk = K >> 6;
  for (int kt = 0; kt < nk; ++kt) {
    __syncthreads();                    // previous iter's readers done
    {
      const char* ga = gA + (size_t)kt * 128;
      const char* gb = gB + (size_t)kt * 128;
      gload_lds16(ga,           lA);
      gload_lds16(gb,           lB);
      gload_lds16(ga +  8 * Kb, lA + 1024);
      gload_lds16(gb +  8 * Kb, lB + 1024);
      gload_lds16(ga + 16 * Kb, lA + 2048);
      gload_lds16(gb + 16 * Kb, lB + 2048);
      gload_lds16(ga + 24 * Kb, lA + 3072);
      gload_lds16(gb + 24 * Kb, lB + 3072);
    }
    __syncthreads();                    // drains vmcnt(0): tile resident
    #pragma unroll
    for (int kk = 0; kk < 2; ++kk) {
      const int off = base16 ^ (kk << 6);
      frag8 a[4], b[4];
      #pragma unroll
      for (int f = 0; f < 4; ++f) {
        a[f] = *(const frag8*)(rowA + f * 2048 + off);
        b[f] = *(const frag8*)(rowB + f * 2048 + off);
      }
      #pragma unroll
      for (int m = 0; m < 4; ++m)
        #pragma unroll
        for (int n = 0; n < 4; ++n)
          mfma_bf16(acc[m][n], a[m], b[n]);
    }
  }

  // ---- epilogue: C/D layout col=lane&15, row=(lane>>4)*4+i (m89-verified) --
  #pragma unroll
  for (int m = 0; m < 4; ++m) {
    const int gr0 = bm + wm * 64 + m * 16 + kq * 4;
    float psum[4] = {0.f, 0.f, 0.f, 0.f};       // MODE 3 row partials
    float inv0 = 1.f, inv1 = 1.f, inv2 = 1.f, inv3 = 1.f;
    if constexpr (MODE == 4) {
      const float4 rs = *(const float4*)&bias0[(size_t)bz * 2048 + gr0];
      inv0 = 1.f / rs.x; inv1 = 1.f / rs.y; inv2 = 1.f / rs.z; inv3 = 1.f / rs.w;
    }
    #pragma unroll
    for (int n = 0; n < 4; ++n) {
      const int gc = bn + wn * 64 + n * 16 + cr;
      float v0 = acc[m][n][0], v1 = acc[m][n][1], v2 = acc[m][n][2], v3 = acc[m][n][3];
      if constexpr (MODE == 3) {
        const float c2v = bias0[(size_t)bz * (size_t)N + gc];
        unsigned short* C = (unsigned short*)Cv + (size_t)bz * (size_t)sC;
        unsigned short e0 = f2bf(__expf((v0 + c2v) * scale));
        unsigned short e1 = f2bf(__expf((v1 + c2v) * scale));
        unsigned short e2 = f2bf(__expf((v2 + c2v) * scale));
        unsigned short e3 = f2bf(__expf((v3 + c2v) * scale));
        C[(size_t)(gr0 + 0) * N + gc] = e0;
        C[(size_t)(gr0 + 1) * N + gc] = e1;
        C[(size_t)(gr0 + 2) * N + gc] = e2;
        C[(size_t)(gr0 + 3) * N + gc] = e3;
        psum[0] += bf2f(e0); psum[1] += bf2f(e1);
        psum[2] += bf2f(e2); psum[3] += bf2f(e3);
      } else if constexpr (MODE == 4) {
        const float bb = bias1[gc];
        float* C = (float*)Cv + (size_t)bz * (size_t)sC;
        C[(size_t)(gr0 + 0) * N + gc] = v0 * inv0 + bb;
        C[(size_t)(gr0 + 1) * N + gc] = v1 * inv1 + bb;
        C[(size_t)(gr0 + 2) * N + gc] = v2 * inv2 + bb;
        C[(size_t)(gr0 + 3) * N + gc] = v3 * inv3 + bb;
      } else if constexpr (MODE == 5) {
        if (bz == 1) {
          // transposed store: v'T[b][d][s], b = gr0>>11, s = gr0&2047, d = gc
          unsigned short* C = (unsigned short*)Cv + (size_t)sC;
          ushort4v u;
          u[0] = f2bf(v0); u[1] = f2bf(v1); u[2] = f2bf(v2); u[3] = f2bf(v3);
          *(ushort4v*)&C[((size_t)(gr0 >> 11) << 21) + (size_t)gc * 2048 + (gr0 & 2047)] = u;
        } else {
          unsigned short* C = (unsigned short*)Cv;
          C[(size_t)(gr0 + 0) * N + gc] = f2bf(v0);
          C[(size_t)(gr0 + 1) * N + gc] = f2bf(v1);
          C[(size_t)(gr0 + 2) * N + gc] = f2bf(v2);
          C[(size_t)(gr0 + 3) * N + gc] = f2bf(v3);
        }
      } else {
        unsigned short* C = (unsigned short*)Cv + (size_t)bz * (size_t)sC;
        C[(size_t)(gr0 + 0) * N + gc] = f2bf(v0);
        C[(size_t)(gr0 + 1) * N + gc] = f2bf(v1);
        C[(size_t)(gr0 + 2) * N + gc] = f2bf(v2);
        C[(size_t)(gr0 + 3) * N + gc] = f2bf(v3);
      }
    }
    if constexpr (MODE == 3) {
      #pragma unroll
      for (int j = 0; j < 4; ++j) {
        float p = psum[j];
        p += __shfl_xor(p, 1);
        p += __shfl_xor(p, 2);
        p += __shfl_xor(p, 4);
        p += __shfl_xor(p, 8);
        if (cr == 0) atomicAdd(&rowsum[(size_t)bz * 2048 + gr0 + j], p);
      }
    }
  }
}

// ---------------------------------------------------------------------------
// fused f32 -> bf16 for three equal-size tensors (blockIdx.y selects)
// ---------------------------------------------------------------------------
__global__ __launch_bounds__(256)
void cvt3_bf16(const float* __restrict__ s0, const float* __restrict__ s1,
               const float* __restrict__ s2, unsigned short* __restrict__ out,
               int n8each)
{
  const float* src = (blockIdx.y == 0) ? s0 : (blockIdx.y == 1) ? s1 : s2;
  unsigned short* dst = out + (size_t)blockIdx.y * ((size_t)n8each * 8);
  int i = blockIdx.x * blockDim.x + threadIdx.x;
  const int stride = gridDim.x * blockDim.x;
  for (; i < n8each; i += stride) {
    const float4* p = (const float4*)src + (size_t)i * 2;
    float4 a = p[0], b = p[1];
    ushort8 o;
    o[0] = f2bf(a.x); o[1] = f2bf(a.y); o[2] = f2bf(a.z); o[3] = f2bf(a.w);
    o[4] = f2bf(b.x); o[5] = f2bf(b.y); o[6] = f2bf(b.z); o[7] = f2bf(b.w);
    *((ushort8*)dst + i) = o;
  }
}

// ---------------------------------------------------------------------------
// prep: one dispatch for all weight-side preprocessing (branch by block range)
//  blocks    0.. 767 : transpose WQ/WK/WV f32 -> bf16 (WQt/WKt/WVt)
//  blocks  768..1791 : Weff row j = sum_h Wl[j,h*1024+:] -> bf16, fused
//                      biasp[j] = Weff_row . bV + bl[j]
//  blocks 1792..1795 : u2[k] = sum_m WK[m,k]*bQ[m]   (no atomics)
//  blocks 1796..1799 : rowsum[8192] = 0
// ---------------------------------------------------------------------------
__global__ __launch_bounds__(256)
void prep_kernel(const float* __restrict__ WQ, const float* __restrict__ WK,
                 const float* __restrict__ WV, const float* __restrict__ Wl,
                 const float* __restrict__ bQ, const float* __restrict__ bV,
                 const float* __restrict__ bl,
                 unsigned short* __restrict__ Wr,   // weight region base
                 float* __restrict__ u2, float* __restrict__ biasp,
                 float* __restrict__ rowsum)
{
  __shared__ float t[64][65];
  const int blk = blockIdx.x;
  const int tid = threadIdx.x;

  if (blk < 768) {
    // ---- transpose-convert: dst[a][b] = src[b][a] ----
    const int z = blk >> 8;             // 0:WQ 1:WK 2:WV
    const int local = blk & 255;
    const float* src = (z == 0) ? WQ : (z == 1) ? WK : WV;
    unsigned short* dst = Wr + (size_t)((z == 0) ? 2 : (z == 1) ? 0 : 3) * 1024 * 1024;
    const int bx  = local & 15;
    const int byy = local >> 4;
    const int tx  = tid & 63;
    const int ty4 = tid >> 6;
    #pragma unroll
    for (int i = 0; i < 16; ++i) {
      const int r = i * 4 + ty4;
      t[r][tx] = src[(size_t)(byy * 64 + r) * 1024 + bx * 64 + tx];
    }
    __syncthreads();
    #pragma unroll
    for (int i = 0; i < 16; ++i) {
      const int r = i * 4 + ty4;
      dst[(size_t)(bx * 64 + r) * 1024 + byy * 64 + tx] = f2bf(t[tx][r]);
    }
  } else if (blk < 1792) {
    // ---- Weff row + biasp ----
    const int j = blk - 768;
    const int d = tid * 4;
    float4 s = make_float4(0.f, 0.f, 0.f, 0.f);
    #pragma unroll
    for (int h = 0; h < 8; ++h) {
      float4 w = *(const float4*)&Wl[(size_t)j * 8192 + h * 1024 + d];
      s.x += w.x; s.y += w.y; s.z += w.z; s.w += w.w;
    }
    unsigned short* Weffb = Wr + (size_t)1024 * 1024;
    ushort4v o;
    o[0] = f2bf(s.x); o[1] = f2bf(s.y); o[2] = f2bf(s.z); o[3] = f2bf(s.w);
    *(ushort4v*)&Weffb[(size_t)j * 1024 + d] = o;
    const float4 bv = *(const float4*)&bV[d];
    float p = s.x * bv.x + s.y * bv.y + s.z * bv.z + s.w * bv.w;
    #pragma unroll
    for (int off = 32; off; off >>= 1) p += __shfl_xor(p, off);
    __shared__ float red[4];
    if ((tid & 63) == 0) red[tid >> 6] = p;
    __syncthreads();
    if (tid == 0) biasp[j] = red[0] + red[1] + red[2] + red[3] + bl[j];
  } else if (blk < 1796) {
    // ---- u2 ----
    const int k = (blk - 1792) * 256 + tid;
    __shared__ float bq[1024];
    #pragma unroll
    for (int i = 0; i < 4; ++i) bq[tid + i * 256] = bQ[tid + i * 256];
    __syncthreads();
    float a = 0.f;
    for (int m = 0; m < 1024; ++m)
      a += WK[(size_t)m * 1024 + k] * bq[m];
    u2[k] = a;
  } else {
    // ---- zero rowsum ----
    const int base = (blk - 1796) * 2048 + tid * 8;
    #pragma unroll
    for (int i = 0; i < 8; ++i) rowsum[base + i] = 0.f;
  }
}

// c2[r] = Kb[r,:] . u2   (wave per row, bf16 K)
__global__ __launch_bounds__(256)
void c2_kernel(const unsigned short* __restrict__ Kb, const float* __restrict__ u2,
               float* __restrict__ c2)
{
  const int lane = threadIdx.x & 63;
  const int w    = threadIdx.x >> 6;
  const int r    = blockIdx.x * 4 + w;
  const unsigned short* kr = Kb + (size_t)r * 1024 + lane * 16;
  ushort8 a = *(const ushort8*)kr;
  ushort8 b = *(const ushort8*)(kr + 8);
  const float* uu = u2 + lane * 16;
  float s = 0.f;
  #pragma unroll
  for (int i = 0; i < 8; ++i) s += bf2f(a[i]) * uu[i];
  #pragma unroll
  for (int i = 0; i < 8; ++i) s += bf2f(b[i]) * uu[8 + i];
  #pragma unroll
  for (int off = 32; off; off >>= 1) s += __shfl_xor(s, off);
  if (lane == 0) c2[r] = s;
}

// ---------------------------------------------------------------------------
extern "C" void kernel_launch(void* const* d_in, const int* in_sizes, int n_in,
                              void* d_out, int out_size, void* d_ws, size_t ws_size,
                              hipStream_t stream)
{
  (void)in_sizes; (void)n_in; (void)out_size; (void)ws_size;

  const float* Q  = (const float*)d_in[0];
  const float* K  = (const float*)d_in[1];
  const float* V  = (const float*)d_in[2];
  const float* WQ = (const float*)d_in[3];
  const float* bQ = (const float*)d_in[4];
  const float* WK = (const float*)d_in[5];
  const float* bK = (const float*)d_in[6];  (void)bK;  // cancels in softmax
  const float* WV = (const float*)d_in[7];
  const float* bV = (const float*)d_in[8];
  const float* Wl = (const float*)d_in[9];
  const float* bl = (const float*)d_in[10];

  const size_t nX = (size_t)8192 * 1024;   // B*S*D
  const size_t nW = (size_t)1024 * 1024;

  // workspace (bf16 elements):
  // [Qb][Vb][Kb][q'][v'T] | weights: [WKt][Weffb][WQt][WVt][Tt][Wve] | f32 vecs
  unsigned short* Qb  = (unsigned short*)d_ws;
  unsigned short* Kb  = Qb + 2 * nX;
  unsigned short* qp  = Qb + 3 * nX;       // q' [8192][1024]
  unsigned short* vpT = Qb + 4 * nX;       // v'T [4][1024][2048]
  unsigned short* Wr  = Qb + 5 * nX;       // weight region base (= WKt)
  unsigned short* WQt   = Wr + 2 * nW;
  unsigned short* Tt    = Wr + 4 * nW;
  float* Fv   = (float*)(Wr + 6 * nW);
  float* rowsum = Fv;                      // 8192
  float* u2     = Fv + 8192;               // 1024
  float* c2     = Fv + 9216;               // 8192
  float* biasp  = Fv + 17408;              // 1024
  unsigned short* P = Qb;                  // [4][2048][2048] overlays Qb+Vb

  const int thr = 256;

  prep_kernel<<<1800, thr, 0, stream>>>(WQ, WK, WV, Wl, bQ, bV, bl,
                                        Wr, u2, biasp, rowsum);
  cvt3_bf16<<<dim3(1024, 3), thr, 0, stream>>>(Q, V, K, Qb, (int)(nX / 8));
  c2_kernel<<<2048, thr, 0, stream>>>(Kb, u2, c2);

  // Tt = WK^T @ WQ (z=0), Wve = Weff @ WV (z=1)
  gemm_bt<0><<<128, thr, 0, stream>>>(
      Wr, WQt, nullptr, nullptr, nullptr, Tt, 1024, 1024, 1.f,
      (long)nW, (long)nW, (long)nW, 8, 8);
  // q' = Qb @ Tt^T (z=0), v'T = (Vb @ Wve^T)^T per batch (z=1)
  gemm_bt<5><<<1024, thr, 0, stream>>>(
      Qb, Tt, nullptr, nullptr, nullptr, qp, 1024, 1024, 1.f,
      (long)nX, (long)nW, (long)nX, 8, 64);
  // P = exp((q' K^T + c2)/32), rowsum accumulated
  gemm_bt<3><<<1024, thr, 0, stream>>>(
      qp, Kb, c2, nullptr, rowsum, P, 2048, 1024, 0.03125f,
      (long)(2048 * 1024), (long)(2048 * 1024), (long)(2048 * 2048), 16, 16);
  // out = (P @ v'T^T)/rowsum + biasp   -> f32
  gemm_bt<4><<<512, thr, 0, stream>>>(
      P, vpT, rowsum, biasp, nullptr, d_out, 1024, 2048, 1.f,
      (long)(2048 * 2048), (long)(1024 * 2048), (long)(2048 * 1024), 8, 16);
}

// Round 6
// 210.226 us; speedup vs baseline: 1.0199x; 1.0199x over previous
//
#include <hip/hip_runtime.h>
#include <hip/hip_bf16.h>
#include <stdint.h>

#define DEV __device__ __forceinline__

typedef __attribute__((ext_vector_type(8))) unsigned short frag8;    // 8 bf16 = 4 VGPR
typedef __attribute__((ext_vector_type(4))) float f32x4;
typedef __attribute__((ext_vector_type(8))) unsigned short ushort8;
typedef __attribute__((ext_vector_type(4))) unsigned short ushort4v;

DEV unsigned short f2bf(float f) {
  union { float f; unsigned u; } x; x.f = f;
  unsigned r = x.u + 0x7fffu + ((x.u >> 16) & 1u);   // RNE
  return (unsigned short)(r >> 16);
}
DEV float bf2f(unsigned short b) {
  union { unsigned u; float f; } x; x.u = ((unsigned)b) << 16;
  return x.f;
}
DEV unsigned short f2bf_hw(float f) {                // compiler emits cvt_pk pairs
  __hip_bfloat16 h = __float2bfloat16(f);
  return *reinterpret_cast<unsigned short*>(&h);
}

DEV void gload_lds16(const void* g, void* l) {
  __builtin_amdgcn_global_load_lds((const __attribute__((address_space(1))) void*)g,
                                   (__attribute__((address_space(3))) void*)l, 16, 0, 0);
}

DEV void mfma_bf16(f32x4& c, frag8 a, frag8 b) {
  asm("v_mfma_f32_16x16x32_bf16 %0, %1, %2, %0" : "+v"(c) : "v"(a), "v"(b));
}

// ---------------------------------------------------------------------------
// C[M,N] = A[M,K]*B[N,K]^T, bf16 in / f32 acc. 128x128 tile, BK=64, 4 waves,
// SINGLE-buffer 32 KiB LDS (round-1/5 proven structure). XOR-swizzled LDS via
// pre-swizzled global source (rule #21). 1D grid + bijective XCD swizzle.
// MODE: 0 = bf16 out
//       3 = scores: e = exp((s + c2[bz*N+gc])*scale), bf16 out, rowsum atomics
//       4 = PV: f32 out = acc/rowsum[row] + biasp[gc]
//       5 = fused q'/v': bz==0 plain bf16; bz==1 per-batch transposed store
// AF32: A operand is f32 in global (Av0 for bz==0, Av1 for bz>=1), converted
//       to bf16 in-register during staging (swizzle applied on ds_write's
//       source column — same involution as the read side).
// ---------------------------------------------------------------------------
template<int MODE, int AF32>
__global__ __launch_bounds__(256)
void gemm_bt(const void* __restrict__ Av0, const void* __restrict__ Av1,
             const unsigned short* __restrict__ Bm,
             const float* __restrict__ bias0, const float* __restrict__ bias1,
             float* __restrict__ rowsum,
             void* __restrict__ Cv,
             int N, int K, float scale,
             long sA, long sB, long sC,
             int nx, int ny)
{
  __shared__ unsigned short ldsA[128 * 64];   // 16 KiB
  __shared__ unsigned short ldsB[128 * 64];   // 16 KiB

  const int tid  = threadIdx.x;
  const int lane = tid & 63;
  const int wave = tid >> 6;
  const int wm   = wave >> 1;           // 2x2 waves, 64x64 each
  const int wn   = wave & 1;

  // ---- bijective XCD swizzle (m204) + grid decomposition ----
  const unsigned nwg = gridDim.x;
  const unsigned orig = blockIdx.x;
  const unsigned qq = nwg >> 3, rr = nwg & 7;
  const unsigned xcd = orig & 7, jj = orig >> 3;
  const unsigned wg = (xcd < rr ? xcd * (qq + 1) : rr * (qq + 1) + (xcd - rr) * qq) + jj;
  const unsigned bx = wg % (unsigned)nx;
  const unsigned tt = wg / (unsigned)nx;
  const unsigned by = tt % (unsigned)ny;
  const unsigned bz = tt / (unsigned)ny;

  const int bm = (int)by * 128;
  const int bn = (int)bx * 128;

  Bm += (size_t)bz * (size_t)sB;

  // ---- staging addresses (per wave: 4 chunks of 1KB = 8 rows each side) ----
  const int r8  = lane >> 3;
  const int l8  = lane & 7;
  const int swz = ((l8 ^ r8) << 4);     // pre-swizzled source byte column
  const size_t Kb = (size_t)K * 2;

  const char* gA = nullptr;             // bf16-A path
  const char* gAf = nullptr;            // f32-A path
  if constexpr (AF32) {
    const float* Abase = (bz == 0) ? (const float*)Av0 : (const float*)Av1;
    gAf = (const char*)Abase + (size_t)(bm + wave * 32 + r8) * (size_t)K * 4
        + (size_t)((l8 ^ r8) * 32);
  } else {
    const unsigned short* Abase = (const unsigned short*)Av0 + (size_t)bz * (size_t)sA;
    gA = (const char*)Abase + (size_t)(bm + wave * 32 + r8) * Kb + swz;
  }
  const char* gB = (const char*)Bm + (size_t)(bn + wave * 32 + r8) * Kb + swz;
  char* lA = (char*)ldsA + wave * 32 * 128;
  char* lB = (char*)ldsB + wave * 32 * 128;

  // ---- fragment read addresses ----
  const int cr = lane & 15;
  const int kq = lane >> 4;
  const int base16 = ((kq ^ (cr & 7)) << 4);
  const char* rowA = (const char*)ldsA + (wm * 64 + cr) * 128;
  const char* rowB = (const char*)ldsB + (wn * 64 + cr) * 128;

  f32x4 acc[4][4];
  #pragma unroll
  for (int m = 0; m < 4; ++m)
    #pragma unroll
    for (int n = 0; n < 4; ++n)
      acc[m][n] = f32x4{0.f, 0.f, 0.f, 0.f};

  const int nk = K >> 6;
  for (int kt = 0; kt < nk; ++kt) {
    __syncthreads();                    // previous iter's readers done
    {
      const char* gb = gB + (size_t)kt * 128;
      gload_lds16(gb,           lB);
      gload_lds16(gb +  8 * Kb, lB + 1024);
      gload_lds16(gb + 16 * Kb, lB + 2048);
      gload_lds16(gb + 24 * Kb, lB + 3072);
      if constexpr (AF32) {
        // f32 loads -> cvt -> ds_write (B gloads already in flight)
        #pragma unroll
        for (int i = 0; i < 4; ++i) {
          const float4* pa = (const float4*)(gAf + (size_t)kt * 256
                                             + (size_t)(i * 8) * (size_t)K * 4);
          float4 x = pa[0], y = pa[1];
          ushort8 o;
          o[0] = f2bf_hw(x.x); o[1] = f2bf_hw(x.y);
          o[2] = f2bf_hw(x.z); o[3] = f2bf_hw(x.w);
          o[4] = f2bf_hw(y.x); o[5] = f2bf_hw(y.y);
          o[6] = f2bf_hw(y.z); o[7] = f2bf_hw(y.w);
          *(ushort8*)(lA + i * 1024 + lane * 16) = o;
        }
      } else {
        const char* ga = gA + (size_t)kt * 128;
        gload_lds16(ga,           lA);
        gload_lds16(ga +  8 * Kb, lA + 1024);
        gload_lds16(ga + 16 * Kb, lA + 2048);
        gload_lds16(ga + 24 * Kb, lA + 3072);
      }
    }
    __syncthreads();                    // drains vm+lgkm: tile resident
    #pragma unroll
    for (int kk = 0; kk < 2; ++kk) {
      const int off = base16 ^ (kk << 6);
      frag8 a[4], b[4];
      #pragma unroll
      for (int f = 0; f < 4; ++f) {
        a[f] = *(const frag8*)(rowA + f * 2048 + off);
        b[f] = *(const frag8*)(rowB + f * 2048 + off);
      }
      #pragma unroll
      for (int m = 0; m < 4; ++m)
        #pragma unroll
        for (int n = 0; n < 4; ++n)
          mfma_bf16(acc[m][n], a[m], b[n]);
    }
  }

  // ---- epilogue: C/D layout col=lane&15, row=(lane>>4)*4+i (m89-verified) --
  #pragma unroll
  for (int m = 0; m < 4; ++m) {
    const int gr0 = bm + wm * 64 + m * 16 + kq * 4;
    float psum[4] = {0.f, 0.f, 0.f, 0.f};       // MODE 3 row partials
    float inv0 = 1.f, inv1 = 1.f, inv2 = 1.f, inv3 = 1.f;
    if constexpr (MODE == 4) {
      const float4 rs = *(const float4*)&bias0[(size_t)bz * 2048 + gr0];
      inv0 = 1.f / rs.x; inv1 = 1.f / rs.y; inv2 = 1.f / rs.z; inv3 = 1.f / rs.w;
    }
    #pragma unroll
    for (int n = 0; n < 4; ++n) {
      const int gc = bn + wn * 64 + n * 16 + cr;
      float v0 = acc[m][n][0], v1 = acc[m][n][1], v2 = acc[m][n][2], v3 = acc[m][n][3];
      if constexpr (MODE == 3) {
        const float c2v = bias0[(size_t)bz * (size_t)N + gc];
        unsigned short* C = (unsigned short*)Cv + (size_t)bz * (size_t)sC;
        unsigned short e0 = f2bf(__expf((v0 + c2v) * scale));
        unsigned short e1 = f2bf(__expf((v1 + c2v) * scale));
        unsigned short e2 = f2bf(__expf((v2 + c2v) * scale));
        unsigned short e3 = f2bf(__expf((v3 + c2v) * scale));
        C[(size_t)(gr0 + 0) * N + gc] = e0;
        C[(size_t)(gr0 + 1) * N + gc] = e1;
        C[(size_t)(gr0 + 2) * N + gc] = e2;
        C[(size_t)(gr0 + 3) * N + gc] = e3;
        psum[0] += bf2f(e0); psum[1] += bf2f(e1);
        psum[2] += bf2f(e2); psum[3] += bf2f(e3);
      } else if constexpr (MODE == 4) {
        const float bb = bias1[gc];
        float* C = (float*)Cv + (size_t)bz * (size_t)sC;
        C[(size_t)(gr0 + 0) * N + gc] = v0 * inv0 + bb;
        C[(size_t)(gr0 + 1) * N + gc] = v1 * inv1 + bb;
        C[(size_t)(gr0 + 2) * N + gc] = v2 * inv2 + bb;
        C[(size_t)(gr0 + 3) * N + gc] = v3 * inv3 + bb;
      } else if constexpr (MODE == 5) {
        if (bz == 1) {
          // transposed store: v'T[b][d][s], b = gr0>>11, s = gr0&2047, d = gc
          unsigned short* C = (unsigned short*)Cv + (size_t)sC;
          ushort4v u;
          u[0] = f2bf(v0); u[1] = f2bf(v1); u[2] = f2bf(v2); u[3] = f2bf(v3);
          *(ushort4v*)&C[((size_t)(gr0 >> 11) << 21) + (size_t)gc * 2048 + (gr0 & 2047)] = u;
        } else {
          unsigned short* C = (unsigned short*)Cv;
          C[(size_t)(gr0 + 0) * N + gc] = f2bf(v0);
          C[(size_t)(gr0 + 1) * N + gc] = f2bf(v1);
          C[(size_t)(gr0 + 2) * N + gc] = f2bf(v2);
          C[(size_t)(gr0 + 3) * N + gc] = f2bf(v3);
        }
      } else {
        unsigned short* C = (unsigned short*)Cv + (size_t)bz * (size_t)sC;
        C[(size_t)(gr0 + 0) * N + gc] = f2bf(v0);
        C[(size_t)(gr0 + 1) * N + gc] = f2bf(v1);
        C[(size_t)(gr0 + 2) * N + gc] = f2bf(v2);
        C[(size_t)(gr0 + 3) * N + gc] = f2bf(v3);
      }
    }
    if constexpr (MODE == 3) {
      #pragma unroll
      for (int j = 0; j < 4; ++j) {
        float p = psum[j];
        p += __shfl_xor(p, 1);
        p += __shfl_xor(p, 2);
        p += __shfl_xor(p, 4);
        p += __shfl_xor(p, 8);
        if (cr == 0) atomicAdd(&rowsum[(size_t)bz * 2048 + gr0 + j], p);
      }
    }
  }
}

// ---------------------------------------------------------------------------
// single f32 -> bf16 convert (vectorized, n8 groups of 8)
// ---------------------------------------------------------------------------
__global__ __launch_bounds__(256)
void cvt1_bf16(const float* __restrict__ src, unsigned short* __restrict__ dst,
               int n8)
{
  int i = blockIdx.x * blockDim.x + threadIdx.x;
  const int stride = gridDim.x * blockDim.x;
  for (; i < n8; i += stride) {
    const float4* p = (const float4*)src + (size_t)i * 2;
    float4 a = p[0], b = p[1];
    ushort8 o;
    o[0] = f2bf(a.x); o[1] = f2bf(a.y); o[2] = f2bf(a.z); o[3] = f2bf(a.w);
    o[4] = f2bf(b.x); o[5] = f2bf(b.y); o[6] = f2bf(b.z); o[7] = f2bf(b.w);
    *((ushort8*)dst + i) = o;
  }
}

// ---------------------------------------------------------------------------
// prep: weight-side preprocessing (branch by block range)
//  blocks    0.. 767 : transpose WQ/WK/WV f32 -> bf16 (WQt/WKt/WVt)
//  blocks  768..1791 : Weff row j = sum_h Wl[j,h*1024+:] -> bf16, fused
//                      biasp[j] = Weff_row . bV + bl[j]
//  blocks 1792..1796 : zero rowsum[8192] + u2[1024] (contiguous 9216 f32)
// ---------------------------------------------------------------------------
__global__ __launch_bounds__(256)
void prep_kernel(const float* __restrict__ WQ, const float* __restrict__ WK,
                 const float* __restrict__ WV, const float* __restrict__ Wl,
                 const float* __restrict__ bV, const float* __restrict__ bl,
                 unsigned short* __restrict__ Wr,   // weight region base
                 float* __restrict__ biasp, float* __restrict__ zbase)
{
  __shared__ float t[64][65];
  const int blk = blockIdx.x;
  const int tid = threadIdx.x;

  if (blk < 768) {
    const int z = blk >> 8;             // 0:WQ 1:WK 2:WV
    const int local = blk & 255;
    const float* src = (z == 0) ? WQ : (z == 1) ? WK : WV;
    unsigned short* dst = Wr + (size_t)((z == 0) ? 2 : (z == 1) ? 0 : 3) * 1024 * 1024;
    const int bx  = local & 15;
    const int byy = local >> 4;
    const int tx  = tid & 63;
    const int ty4 = tid >> 6;
    #pragma unroll
    for (int i = 0; i < 16; ++i) {
      const int r = i * 4 + ty4;
      t[r][tx] = src[(size_t)(byy * 64 + r) * 1024 + bx * 64 + tx];
    }
    __syncthreads();
    #pragma unroll
    for (int i = 0; i < 16; ++i) {
      const int r = i * 4 + ty4;
      dst[(size_t)(bx * 64 + r) * 1024 + byy * 64 + tx] = f2bf(t[tx][r]);
    }
  } else if (blk < 1792) {
    const int j = blk - 768;
    const int d = tid * 4;
    float4 s = make_float4(0.f, 0.f, 0.f, 0.f);
    #pragma unroll
    for (int h = 0; h < 8; ++h) {
      float4 w = *(const float4*)&Wl[(size_t)j * 8192 + h * 1024 + d];
      s.x += w.x; s.y += w.y; s.z += w.z; s.w += w.w;
    }
    unsigned short* Weffb = Wr + (size_t)1024 * 1024;
    ushort4v o;
    o[0] = f2bf(s.x); o[1] = f2bf(s.y); o[2] = f2bf(s.z); o[3] = f2bf(s.w);
    *(ushort4v*)&Weffb[(size_t)j * 1024 + d] = o;
    const float4 bv = *(const float4*)&bV[d];
    float p = s.x * bv.x + s.y * bv.y + s.z * bv.z + s.w * bv.w;
    #pragma unroll
    for (int off = 32; off; off >>= 1) p += __shfl_xor(p, off);
    __shared__ float red[4];
    if ((tid & 63) == 0) red[tid >> 6] = p;
    __syncthreads();
    if (tid == 0) biasp[j] = red[0] + red[1] + red[2] + red[3] + bl[j];
  } else {
    const int i = (blk - 1792) * 2048 + tid * 8;
    if (i < 9216) {
      #pragma unroll
      for (int j = 0; j < 8; ++j) zbase[i + j] = 0.f;
    }
  }
}

// u2[k] += sum_{m in chunk} WK[m,k] * bQ[m]   (grid.x: k-chunks, grid.y: m-chunks)
__global__ __launch_bounds__(256)
void u2_kernel(const float* __restrict__ WK, const float* __restrict__ bQ,
               float* __restrict__ u2)
{
  const int k = blockIdx.x * 256 + threadIdx.x;
  const int m0 = blockIdx.y * 256;
  float a = 0.f;
  for (int m = m0; m < m0 + 256; ++m)
    a += WK[(size_t)m * 1024 + k] * bQ[m];
  atomicAdd(&u2[k], a);
}

// c2[r] = Kb[r,:] . u2   (wave per row, bf16 K)
__global__ __launch_bounds__(256)
void c2_kernel(const unsigned short* __restrict__ Kb, const float* __restrict__ u2,
               float* __restrict__ c2)
{
  const int lane = threadIdx.x & 63;
  const int w    = threadIdx.x >> 6;
  const int r    = blockIdx.x * 4 + w;
  const unsigned short* kr = Kb + (size_t)r * 1024 + lane * 16;
  ushort8 a = *(const ushort8*)kr;
  ushort8 b = *(const ushort8*)(kr + 8);
  const float* uu = u2 + lane * 16;
  float s = 0.f;
  #pragma unroll
  for (int i = 0; i < 8; ++i) s += bf2f(a[i]) * uu[i];
  #pragma unroll
  for (int i = 0; i < 8; ++i) s += bf2f(b[i]) * uu[8 + i];
  #pragma unroll
  for (int off = 32; off; off >>= 1) s += __shfl_xor(s, off);
  if (lane == 0) c2[r] = s;
}

// ---------------------------------------------------------------------------
extern "C" void kernel_launch(void* const* d_in, const int* in_sizes, int n_in,
                              void* d_out, int out_size, void* d_ws, size_t ws_size,
                              hipStream_t stream)
{
  (void)in_sizes; (void)n_in; (void)out_size; (void)ws_size;

  const float* Q  = (const float*)d_in[0];
  const float* K  = (const float*)d_in[1];
  const float* V  = (const float*)d_in[2];
  const float* WQ = (const float*)d_in[3];
  const float* bQ = (const float*)d_in[4];
  const float* WK = (const float*)d_in[5];
  const float* bK = (const float*)d_in[6];  (void)bK;  // cancels in softmax
  const float* WV = (const float*)d_in[7];
  const float* bV = (const float*)d_in[8];
  const float* Wl = (const float*)d_in[9];
  const float* bl = (const float*)d_in[10];

  const size_t nX = (size_t)8192 * 1024;   // B*S*D
  const size_t nW = (size_t)1024 * 1024;

  // workspace (bf16 elements):
  // [P: 2*nX][Kb][q'][v'T] | weights: [WKt][Weffb][WQt][WVt][Tt][Wve] | f32 vecs
  unsigned short* Pb  = (unsigned short*)d_ws;   // [4][2048][2048] = 2*nX
  unsigned short* Kb  = Pb + 2 * nX;
  unsigned short* qp  = Pb + 3 * nX;       // q' [8192][1024]
  unsigned short* vpT = Pb + 4 * nX;       // v'T [4][1024][2048]
  unsigned short* Wr  = Pb + 5 * nX;       // weight region base (= WKt)
  unsigned short* WQt = Wr + 2 * nW;
  unsigned short* Tt  = Wr + 4 * nW;
  float* Fv   = (float*)(Wr + 6 * nW);
  float* rowsum = Fv;                      // 8192
  float* u2     = Fv + 8192;               // 1024
  float* c2     = Fv + 9216;               // 8192
  float* biasp  = Fv + 17408;              // 1024

  const int thr = 256;

  prep_kernel<<<1797, thr, 0, stream>>>(WQ, WK, WV, Wl, bV, bl, Wr, biasp, rowsum);
  u2_kernel<<<dim3(4, 4), thr, 0, stream>>>(WK, bQ, u2);
  cvt1_bf16<<<1024, thr, 0, stream>>>(K, Kb, (int)(nX / 8));
  c2_kernel<<<2048, thr, 0, stream>>>(Kb, u2, c2);

  // Tt = WK^T @ WQ (z=0), Wve = Weff @ WV (z=1)
  gemm_bt<0, 0><<<128, thr, 0, stream>>>(
      Wr, nullptr, WQt, nullptr, nullptr, nullptr, Tt, 1024, 1024, 1.f,
      (long)nW, (long)nW, (long)nW, 8, 8);
  // q' = Q @ Tt^T (z=0), v'T = (V @ Wve^T)^T per batch (z=1); A is f32 global
  gemm_bt<5, 1><<<1024, thr, 0, stream>>>(
      Q, V, Tt, nullptr, nullptr, nullptr, qp, 1024, 1024, 1.f,
      0, (long)nW, (long)nX, 8, 64);
  // P = exp((q' K^T + c2)/32), rowsum accumulated
  gemm_bt<3, 0><<<1024, thr, 0, stream>>>(
      qp, nullptr, Kb, c2, nullptr, rowsum, Pb, 2048, 1024, 0.03125f,
      (long)(2048 * 1024), (long)(2048 * 1024), (long)(2048 * 2048), 16, 16);
  // out = (P @ v'T^T)/rowsum + biasp   -> f32
  gemm_bt<4, 0><<<512, thr, 0, stream>>>(
      Pb, nullptr, vpT, rowsum, biasp, nullptr, d_out, 1024, 2048, 1.f,
      (long)(2048 * 2048), (long)(1024 * 2048), (long)(2048 * 1024), 8, 16);
}

// Round 7
// 209.779 us; speedup vs baseline: 1.0220x; 1.0021x over previous
//
#include <hip/hip_runtime.h>
#include <stdint.h>

#define DEV __device__ __forceinline__

typedef __attribute__((ext_vector_type(8))) unsigned short frag8;    // 8 bf16 = 4 VGPR
typedef __attribute__((ext_vector_type(4))) float f32x4;
typedef __attribute__((ext_vector_type(8))) unsigned short ushort8;
typedef __attribute__((ext_vector_type(4))) unsigned short ushort4v;

DEV unsigned short f2bf(float f) {
  union { float f; unsigned u; } x; x.f = f;
  unsigned r = x.u + 0x7fffu + ((x.u >> 16) & 1u);   // RNE
  return (unsigned short)(r >> 16);
}
DEV float bf2f(unsigned short b) {
  union { unsigned u; float f; } x; x.u = ((unsigned)b) << 16;
  return x.f;
}

DEV void gload_lds16(const void* g, void* l) {
  __builtin_amdgcn_global_load_lds((const __attribute__((address_space(1))) void*)g,
                                   (__attribute__((address_space(3))) void*)l, 16, 0, 0);
}

DEV void mfma_bf16(f32x4& c, frag8 a, frag8 b) {
  asm("v_mfma_f32_16x16x32_bf16 %0, %1, %2, %0" : "+v"(c) : "v"(a), "v"(b));
}

DEV void wait_vm6_bar() {
  asm volatile("s_waitcnt vmcnt(6)" ::: "memory");
  __builtin_amdgcn_s_barrier();
  __builtin_amdgcn_sched_barrier(0);
}
DEV void wait_vm0_bar() {
  asm volatile("s_waitcnt vmcnt(0)" ::: "memory");
  __builtin_amdgcn_s_barrier();
  __builtin_amdgcn_sched_barrier(0);
}

// ---------------------------------------------------------------------------
// gemm256: C[M,N] = A[M,K]*B[N,K]^T, bf16/f32-acc. 128x256 tile, BK=64,
// 8 waves (2M x 4N, per-wave 64x64 = same fragment geometry as the proven
// 128^2 kernel). THREE LDS buffers (48 KB each, 144 KB total): compute tile t,
// tile t+1 resident/in-flight, stage tile t+2 -> counted vmcnt(6) boundary,
// never a mid-loop drain; t+1's loads get a full tile of MFMA to land.
// XOR-swizzle via pre-swizzled global source (rule #21, zero conflicts
// measured). Bijective XCD swizzle. setprio(1) around MFMA clusters (T5).
// MODE: 3 = scores: e=exp((s+c2)*scale), bf16 out, rowsum atomics
//       4 = PV: f32 out = acc/rowsum[row] + biasp[gc]
//       5 = fused q'/v': bz==0 plain bf16; bz==1 per-batch transposed store
// ---------------------------------------------------------------------------
template<int MODE>
__global__ __launch_bounds__(512)
void gemm256(const unsigned short* __restrict__ A,
             const unsigned short* __restrict__ Bm,
             const float* __restrict__ bias0, const float* __restrict__ bias1,
             float* __restrict__ rowsum,
             void* __restrict__ Cv,
             int N, int K, float scale,
             long sA, long sB, long sC,
             int nx, int ny)
{
  __shared__ unsigned short lds[3][24576];   // per buf: A[128*64] then B[256*64]

  const int tid  = threadIdx.x;
  const int lane = tid & 63;
  const int wave = tid >> 6;            // 0..7
  const int wm   = wave >> 2;           // 0..1  (row half)
  const int wn   = wave & 3;            // 0..3  (col quarter)

  // ---- bijective XCD swizzle (m204) + grid decomposition ----
  const unsigned nwg = gridDim.x;
  const unsigned orig = blockIdx.x;
  const unsigned qq = nwg >> 3, rr = nwg & 7;
  const unsigned xcd = orig & 7, jj = orig >> 3;
  const unsigned wg = (xcd < rr ? xcd * (qq + 1) : rr * (qq + 1) + (xcd - rr) * qq) + jj;
  const unsigned bx = wg % (unsigned)nx;
  const unsigned tt = wg / (unsigned)nx;
  const unsigned by = tt % (unsigned)ny;
  const unsigned bz = tt / (unsigned)ny;

  const int bm = (int)by * 128;
  const int bn = (int)bx * 256;

  A  += (size_t)bz * (size_t)sA;
  Bm += (size_t)bz * (size_t)sB;

  // ---- staging addresses: 512 thr, 16B each -> 64 rows per load-step ----
  const int r8  = lane >> 3;            // row-within-8 (= row&7 of its LDS row)
  const int l8  = lane & 7;             // 16B chunk in 128B row
  const int swz = ((l8 ^ r8) << 4);     // pre-swizzled global byte column
  const size_t Kb = (size_t)K * 2;

  const char* gA = (const char*)A  + (size_t)(bm + wave * 8 + r8) * Kb + swz;
  const char* gB = (const char*)Bm + (size_t)(bn + wave * 8 + r8) * Kb + swz;
  const int ldsoff = wave * 8 * 128;    // wave-uniform byte base within region

  // ---- fragment read addresses (identical mapping to proven kernel) ----
  const int cr = lane & 15;
  const int kq = lane >> 4;
  const int base16 = ((kq ^ (cr & 7)) << 4);
  const int rowAoff = (wm * 64 + cr) * 128;
  const int rowBoff = 16384 + (wn * 64 + cr) * 128;   // B region at +8192 shorts

  f32x4 acc[4][4];
  #pragma unroll
  for (int m = 0; m < 4; ++m)
    #pragma unroll
    for (int n = 0; n < 4; ++n)
      acc[m][n] = f32x4{0.f, 0.f, 0.f, 0.f};

  auto STAGE = [&](int t, int buf) {    // 6 loads/thread: A x2 steps, B x4
    const char* ga = gA + (size_t)t * 128;
    const char* gb = gB + (size_t)t * 128;
    char* la = (char*)&lds[buf][0]    + ldsoff;
    char* lb = (char*)&lds[buf][8192] + ldsoff;
    gload_lds16(ga,                 la);
    gload_lds16(ga +  64 * Kb,      la +  64 * 128);
    gload_lds16(gb,                 lb);
    gload_lds16(gb +  64 * Kb,      lb +  64 * 128);
    gload_lds16(gb + 128 * Kb,      lb + 128 * 128);
    gload_lds16(gb + 192 * Kb,      lb + 192 * 128);
  };
  auto COMPUTE = [&](int buf) {
    const char* ra = (const char*)&lds[buf][0] + rowAoff;
    const char* rb = (const char*)&lds[buf][0] + rowBoff;
    #pragma unroll
    for (int kk = 0; kk < 2; ++kk) {
      const int off = base16 ^ (kk << 6);
      frag8 a[4], b[4];
      #pragma unroll
      for (int f = 0; f < 4; ++f) {
        a[f] = *(const frag8*)(ra + f * 2048 + off);
        b[f] = *(const frag8*)(rb + f * 2048 + off);
      }
      __builtin_amdgcn_s_setprio(1);
      #pragma unroll
      for (int m = 0; m < 4; ++m)
        #pragma unroll
        for (int n = 0; n < 4; ++n)
          mfma_bf16(acc[m][n], a[m], b[n]);
      __builtin_amdgcn_s_setprio(0);
    }
  };

  const int nk = K >> 6;                // >= 16 here
  STAGE(0, 0);
  STAGE(1, 1);
  wait_vm6_bar();                       // tile0 resident; tile1 in flight
  int cb = 0, sb = 2;
  for (int t = 0; t < nk; ++t) {
    if (t + 2 < nk) STAGE(t + 2, sb);
    COMPUTE(cb);
    if (t + 1 < nk) {
      if (t + 2 < nk) wait_vm6_bar();   // t+1 resident; t+2 stays in flight
      else            wait_vm0_bar();   // tail
    }
    cb = (cb + 1 == 3) ? 0 : cb + 1;
    sb = (sb + 1 == 3) ? 0 : sb + 1;
  }

  // ---- epilogue: C/D layout col=lane&15, row=(lane>>4)*4+i (m89-verified) --
  #pragma unroll
  for (int m = 0; m < 4; ++m) {
    const int gr0 = bm + wm * 64 + m * 16 + kq * 4;
    float psum[4] = {0.f, 0.f, 0.f, 0.f};
    float inv0 = 1.f, inv1 = 1.f, inv2 = 1.f, inv3 = 1.f;
    if constexpr (MODE == 4) {
      const float4 rs = *(const float4*)&bias0[(size_t)bz * 2048 + gr0];
      inv0 = 1.f / rs.x; inv1 = 1.f / rs.y; inv2 = 1.f / rs.z; inv3 = 1.f / rs.w;
    }
    #pragma unroll
    for (int n = 0; n < 4; ++n) {
      const int gc = bn + wn * 64 + n * 16 + cr;
      float v0 = acc[m][n][0], v1 = acc[m][n][1], v2 = acc[m][n][2], v3 = acc[m][n][3];
      if constexpr (MODE == 3) {
        const float c2v = bias0[(size_t)bz * (size_t)N + gc];
        unsigned short* C = (unsigned short*)Cv + (size_t)bz * (size_t)sC;
        unsigned short e0 = f2bf(__expf((v0 + c2v) * scale));
        unsigned short e1 = f2bf(__expf((v1 + c2v) * scale));
        unsigned short e2 = f2bf(__expf((v2 + c2v) * scale));
        unsigned short e3 = f2bf(__expf((v3 + c2v) * scale));
        C[(size_t)(gr0 + 0) * N + gc] = e0;
        C[(size_t)(gr0 + 1) * N + gc] = e1;
        C[(size_t)(gr0 + 2) * N + gc] = e2;
        C[(size_t)(gr0 + 3) * N + gc] = e3;
        psum[0] += bf2f(e0); psum[1] += bf2f(e1);
        psum[2] += bf2f(e2); psum[3] += bf2f(e3);
      } else if constexpr (MODE == 4) {
        const float bb = bias1[gc];
        float* C = (float*)Cv + (size_t)bz * (size_t)sC;
        C[(size_t)(gr0 + 0) * N + gc] = v0 * inv0 + bb;
        C[(size_t)(gr0 + 1) * N + gc] = v1 * inv1 + bb;
        C[(size_t)(gr0 + 2) * N + gc] = v2 * inv2 + bb;
        C[(size_t)(gr0 + 3) * N + gc] = v3 * inv3 + bb;
      } else {  // MODE 5
        if (bz == 1) {
          unsigned short* C = (unsigned short*)Cv + (size_t)sC;
          ushort4v u;
          u[0] = f2bf(v0); u[1] = f2bf(v1); u[2] = f2bf(v2); u[3] = f2bf(v3);
          *(ushort4v*)&C[((size_t)(gr0 >> 11) << 21) + (size_t)gc * 2048 + (gr0 & 2047)] = u;
        } else {
          unsigned short* C = (unsigned short*)Cv;
          C[(size_t)(gr0 + 0) * N + gc] = f2bf(v0);
          C[(size_t)(gr0 + 1) * N + gc] = f2bf(v1);
          C[(size_t)(gr0 + 2) * N + gc] = f2bf(v2);
          C[(size_t)(gr0 + 3) * N + gc] = f2bf(v3);
        }
      }
    }
    if constexpr (MODE == 3) {
      #pragma unroll
      for (int j = 0; j < 4; ++j) {
        float p = psum[j];
        p += __shfl_xor(p, 1);
        p += __shfl_xor(p, 2);
        p += __shfl_xor(p, 4);
        p += __shfl_xor(p, 8);
        if (cr == 0) atomicAdd(&rowsum[(size_t)bz * 2048 + gr0 + j], p);
      }
    }
  }
}

// ---------------------------------------------------------------------------
// gemm_bt0: proven 128x128 single-buffer kernel, bf16 out (used for Tt/Wve)
// ---------------------------------------------------------------------------
__global__ __launch_bounds__(256)
void gemm_bt0(const unsigned short* __restrict__ A,
              const unsigned short* __restrict__ Bm,
              void* __restrict__ Cv,
              int N, int K,
              long sA, long sB, long sC,
              int nx, int ny)
{
  __shared__ unsigned short ldsA[128 * 64];
  __shared__ unsigned short ldsB[128 * 64];

  const int tid  = threadIdx.x;
  const int lane = tid & 63;
  const int wave = tid >> 6;
  const int wm   = wave >> 1;
  const int wn   = wave & 1;

  const unsigned nwg = gridDim.x;
  const unsigned orig = blockIdx.x;
  const unsigned qq = nwg >> 3, rr = nwg & 7;
  const unsigned xcd = orig & 7, jj = orig >> 3;
  const unsigned wg = (xcd < rr ? xcd * (qq + 1) : rr * (qq + 1) + (xcd - rr) * qq) + jj;
  const unsigned bx = wg % (unsigned)nx;
  const unsigned tt = wg / (unsigned)nx;
  const unsigned by = tt % (unsigned)ny;
  const unsigned bz = tt / (unsigned)ny;

  const int bm = (int)by * 128;
  const int bn = (int)bx * 128;

  A  += (size_t)bz * (size_t)sA;
  Bm += (size_t)bz * (size_t)sB;

  const int r8  = lane >> 3;
  const int l8  = lane & 7;
  const int swz = ((l8 ^ r8) << 4);
  const size_t Kb = (size_t)K * 2;

  const char* gA = (const char*)A  + (size_t)(bm + wave * 32 + r8) * Kb + swz;
  const char* gB = (const char*)Bm + (size_t)(bn + wave * 32 + r8) * Kb + swz;
  char* lA = (char*)ldsA + wave * 32 * 128;
  char* lB = (char*)ldsB + wave * 32 * 128;

  const int cr = lane & 15;
  const int kq = lane >> 4;
  const int base16 = ((kq ^ (cr & 7)) << 4);
  const char* rowA = (const char*)ldsA + (wm * 64 + cr) * 128;
  const char* rowB = (const char*)ldsB + (wn * 64 + cr) * 128;

  f32x4 acc[4][4];
  #pragma unroll
  for (int m = 0; m < 4; ++m)
    #pragma unroll
    for (int n = 0; n < 4; ++n)
      acc[m][n] = f32x4{0.f, 0.f, 0.f, 0.f};

  const int nk = K >> 6;
  for (int kt = 0; kt < nk; ++kt) {
    __syncthreads();
    {
      const char* ga = gA + (size_t)kt * 128;
      const char* gb = gB + (size_t)kt * 128;
      gload_lds16(ga,           lA);
      gload_lds16(gb,           lB);
      gload_lds16(ga +  8 * Kb, lA + 1024);
      gload_lds16(gb +  8 * Kb, lB + 1024);
      gload_lds16(ga + 16 * Kb, lA + 2048);
      gload_lds16(gb + 16 * Kb, lB + 2048);
      gload_lds16(ga + 24 * Kb, lA + 3072);
      gload_lds16(gb + 24 * Kb, lB + 3072);
    }
    __syncthreads();
    #pragma unroll
    for (int kk = 0; kk < 2; ++kk) {
      const int off = base16 ^ (kk << 6);
      frag8 a[4], b[4];
      #pragma unroll
      for (int f = 0; f < 4; ++f) {
        a[f] = *(const frag8*)(rowA + f * 2048 + off);
        b[f] = *(const frag8*)(rowB + f * 2048 + off);
      }
      #pragma unroll
      for (int m = 0; m < 4; ++m)
        #pragma unroll
        for (int n = 0; n < 4; ++n)
          mfma_bf16(acc[m][n], a[m], b[n]);
    }
  }

  #pragma unroll
  for (int m = 0; m < 4; ++m) {
    const int gr0 = bm + wm * 64 + m * 16 + kq * 4;
    #pragma unroll
    for (int n = 0; n < 4; ++n) {
      const int gc = bn + wn * 64 + n * 16 + cr;
      unsigned short* C = (unsigned short*)Cv + (size_t)bz * (size_t)sC;
      C[(size_t)(gr0 + 0) * N + gc] = f2bf(acc[m][n][0]);
      C[(size_t)(gr0 + 1) * N + gc] = f2bf(acc[m][n][1]);
      C[(size_t)(gr0 + 2) * N + gc] = f2bf(acc[m][n][2]);
      C[(size_t)(gr0 + 3) * N + gc] = f2bf(acc[m][n][3]);
    }
  }
}

// ---------------------------------------------------------------------------
// fused f32 -> bf16 for three equal-size tensors (blockIdx.y selects)
// ---------------------------------------------------------------------------
__global__ __launch_bounds__(256)
void cvt3_bf16(const float* __restrict__ s0, const float* __restrict__ s1,
               const float* __restrict__ s2, unsigned short* __restrict__ out,
               int n8each)
{
  const float* src = (blockIdx.y == 0) ? s0 : (blockIdx.y == 1) ? s1 : s2;
  unsigned short* dst = out + (size_t)blockIdx.y * ((size_t)n8each * 8);
  int i = blockIdx.x * blockDim.x + threadIdx.x;
  const int stride = gridDim.x * blockDim.x;
  for (; i < n8each; i += stride) {
    const float4* p = (const float4*)src + (size_t)i * 2;
    float4 a = p[0], b = p[1];
    ushort8 o;
    o[0] = f2bf(a.x); o[1] = f2bf(a.y); o[2] = f2bf(a.z); o[3] = f2bf(a.w);
    o[4] = f2bf(b.x); o[5] = f2bf(b.y); o[6] = f2bf(b.z); o[7] = f2bf(b.w);
    *((ushort8*)dst + i) = o;
  }
}

// ---------------------------------------------------------------------------
// prep: weight-side preprocessing (branch by block range)
//  blocks    0.. 767 : transpose WQ/WK/WV f32 -> bf16 (WQt/WKt/WVt)
//  blocks  768..1791 : Weff row + fused biasp
//  blocks 1792..1796 : zero rowsum[8192] + u2[1024]
// ---------------------------------------------------------------------------
__global__ __launch_bounds__(256)
void prep_kernel(const float* __restrict__ WQ, const float* __restrict__ WK,
                 const float* __restrict__ WV, const float* __restrict__ Wl,
                 const float* __restrict__ bV, const float* __restrict__ bl,
                 unsigned short* __restrict__ Wr,
                 float* __restrict__ biasp, float* __restrict__ zbase)
{
  __shared__ float t[64][65];
  const int blk = blockIdx.x;
  const int tid = threadIdx.x;

  if (blk < 768) {
    const int z = blk >> 8;
    const int local = blk & 255;
    const float* src = (z == 0) ? WQ : (z == 1) ? WK : WV;
    unsigned short* dst = Wr + (size_t)((z == 0) ? 2 : (z == 1) ? 0 : 3) * 1024 * 1024;
    const int bx  = local & 15;
    const int byy = local >> 4;
    const int tx  = tid & 63;
    const int ty4 = tid >> 6;
    #pragma unroll
    for (int i = 0; i < 16; ++i) {
      const int r = i * 4 + ty4;
      t[r][tx] = src[(size_t)(byy * 64 + r) * 1024 + bx * 64 + tx];
    }
    __syncthreads();
    #pragma unroll
    for (int i = 0; i < 16; ++i) {
      const int r = i * 4 + ty4;
      dst[(size_t)(bx * 64 + r) * 1024 + byy * 64 + tx] = f2bf(t[tx][r]);
    }
  } else if (blk < 1792) {
    const int j = blk - 768;
    const int d = tid * 4;
    float4 s = make_float4(0.f, 0.f, 0.f, 0.f);
    #pragma unroll
    for (int h = 0; h < 8; ++h) {
      float4 w = *(const float4*)&Wl[(size_t)j * 8192 + h * 1024 + d];
      s.x += w.x; s.y += w.y; s.z += w.z; s.w += w.w;
    }
    unsigned short* Weffb = Wr + (size_t)1024 * 1024;
    ushort4v o;
    o[0] = f2bf(s.x); o[1] = f2bf(s.y); o[2] = f2bf(s.z); o[3] = f2bf(s.w);
    *(ushort4v*)&Weffb[(size_t)j * 1024 + d] = o;
    const float4 bv = *(const float4*)&bV[d];
    float p = s.x * bv.x + s.y * bv.y + s.z * bv.z + s.w * bv.w;
    #pragma unroll
    for (int off = 32; off; off >>= 1) p += __shfl_xor(p, off);
    __shared__ float red[4];
    if ((tid & 63) == 0) red[tid >> 6] = p;
    __syncthreads();
    if (tid == 0) biasp[j] = red[0] + red[1] + red[2] + red[3] + bl[j];
  } else {
    const int i = (blk - 1792) * 2048 + tid * 8;
    if (i < 9216) {
      #pragma unroll
      for (int j = 0; j < 8; ++j) zbase[i + j] = 0.f;
    }
  }
}

// u2[k] += sum_{m in chunk} WK[m,k] * bQ[m]
__global__ __launch_bounds__(256)
void u2_kernel(const float* __restrict__ WK, const float* __restrict__ bQ,
               float* __restrict__ u2)
{
  const int k = blockIdx.x * 256 + threadIdx.x;
  const int m0 = blockIdx.y * 256;
  float a = 0.f;
  for (int m = m0; m < m0 + 256; ++m)
    a += WK[(size_t)m * 1024 + k] * bQ[m];
  atomicAdd(&u2[k], a);
}

// c2[r] = Kb[r,:] . u2
__global__ __launch_bounds__(256)
void c2_kernel(const unsigned short* __restrict__ Kb, const float* __restrict__ u2,
               float* __restrict__ c2)
{
  const int lane = threadIdx.x & 63;
  const int w    = threadIdx.x >> 6;
  const int r    = blockIdx.x * 4 + w;
  const unsigned short* kr = Kb + (size_t)r * 1024 + lane * 16;
  ushort8 a = *(const ushort8*)kr;
  ushort8 b = *(const ushort8*)(kr + 8);
  const float* uu = u2 + lane * 16;
  float s = 0.f;
  #pragma unroll
  for (int i = 0; i < 8; ++i) s += bf2f(a[i]) * uu[i];
  #pragma unroll
  for (int i = 0; i < 8; ++i) s += bf2f(b[i]) * uu[8 + i];
  #pragma unroll
  for (int off = 32; off; off >>= 1) s += __shfl_xor(s, off);
  if (lane == 0) c2[r] = s;
}

// ---------------------------------------------------------------------------
extern "C" void kernel_launch(void* const* d_in, const int* in_sizes, int n_in,
                              void* d_out, int out_size, void* d_ws, size_t ws_size,
                              hipStream_t stream)
{
  (void)in_sizes; (void)n_in; (void)out_size; (void)ws_size;

  const float* Q  = (const float*)d_in[0];
  const float* K  = (const float*)d_in[1];
  const float* V  = (const float*)d_in[2];
  const float* WQ = (const float*)d_in[3];
  const float* bQ = (const float*)d_in[4];
  const float* WK = (const float*)d_in[5];
  const float* bK = (const float*)d_in[6];  (void)bK;  // cancels in softmax
  const float* WV = (const float*)d_in[7];
  const float* bV = (const float*)d_in[8];
  const float* Wl = (const float*)d_in[9];
  const float* bl = (const float*)d_in[10];

  const size_t nX = (size_t)8192 * 1024;   // B*S*D
  const size_t nW = (size_t)1024 * 1024;

  // workspace (bf16 elements):
  // [Qb][Vb][Kb][q'][v'T] | weights: [WKt][Weffb][WQt][WVt][Tt][Wve] | f32 vecs
  // P ([4][2048][2048] = 2*nX) overlays Qb+Vb after they are consumed.
  unsigned short* Qb  = (unsigned short*)d_ws;
  unsigned short* Kb  = Qb + 2 * nX;
  unsigned short* qp  = Qb + 3 * nX;       // q' [8192][1024]; v'T at +nX
  unsigned short* Wr  = Qb + 5 * nX;       // weight region base (= WKt)
  unsigned short* WQt = Wr + 2 * nW;
  unsigned short* Tt  = Wr + 4 * nW;
  float* Fv   = (float*)(Wr + 6 * nW);
  float* rowsum = Fv;                      // 8192
  float* u2     = Fv + 8192;               // 1024
  float* c2     = Fv + 9216;               // 8192
  float* biasp  = Fv + 17408;              // 1024
  unsigned short* Pb = Qb;                 // overlays [0, 2*nX)

  const int thr = 256;

  prep_kernel<<<1797, thr, 0, stream>>>(WQ, WK, WV, Wl, bV, bl, Wr, biasp, rowsum);
  u2_kernel<<<dim3(4, 4), thr, 0, stream>>>(WK, bQ, u2);
  cvt3_bf16<<<dim3(1024, 3), thr, 0, stream>>>(Q, V, K, Qb, (int)(nX / 8));
  c2_kernel<<<2048, thr, 0, stream>>>(Kb, u2, c2);

  // Tt = WK^T @ WQ (z=0), Wve = Weff @ WV (z=1)   [proven 128^2 kernel]
  gemm_bt0<<<128, thr, 0, stream>>>(
      Wr, WQt, Tt, 1024, 1024, (long)nW, (long)nW, (long)nW, 8, 8);
  // q' = Qb @ Tt^T (bz=0), v'T = (Vb @ Wve^T)^T per batch (bz=1)
  gemm256<5><<<512, 512, 0, stream>>>(
      Qb, Tt, nullptr, nullptr, nullptr, qp, 1024, 1024, 1.f,
      (long)nX, (long)nW, (long)nX, 4, 64);
  // P = exp((q' K^T + c2)/32), rowsum accumulated
  gemm256<3><<<512, 512, 0, stream>>>(
      qp, Kb, c2, nullptr, rowsum, Pb, 2048, 1024, 0.03125f,
      (long)(2048 * 1024), (long)(2048 * 1024), (long)(2048 * 2048), 8, 16);
  // out = (P @ v'T^T)/rowsum + biasp   -> f32
  gemm256<4><<<256, 512, 0, stream>>>(
      Pb, qp + nX, rowsum, biasp, nullptr, d_out, 1024, 2048, 1.f,
      (long)(2048 * 2048), (long)(1024 * 2048), (long)(2048 * 1024), 4, 16);
}

// Round 8
// 201.550 us; speedup vs baseline: 1.0638x; 1.0408x over previous
//
#include <hip/hip_runtime.h>
#include <hip/hip_bf16.h>
#include <stdint.h>

#define DEV __device__ __forceinline__

typedef __attribute__((ext_vector_type(8))) unsigned short frag8;    // 8 bf16 = 4 VGPR
typedef __attribute__((ext_vector_type(4))) float f32x4;
typedef __attribute__((ext_vector_type(8))) unsigned short ushort8;
typedef __attribute__((ext_vector_type(4))) unsigned short ushort4v;

DEV unsigned short f2bf(float f) {
  union { float f; unsigned u; } x; x.f = f;
  unsigned r = x.u + 0x7fffu + ((x.u >> 16) & 1u);   // RNE
  return (unsigned short)(r >> 16);
}
DEV float bf2f(unsigned short b) {
  union { unsigned u; float f; } x; x.u = ((unsigned)b) << 16;
  return x.f;
}
DEV unsigned short f2bf_hw(float f) {                // hw cvt (RNE), compiler pairs
  __hip_bfloat16 h = __float2bfloat16(f);
  return *reinterpret_cast<unsigned short*>(&h);
}

DEV void gload_lds16(const void* g, void* l) {
  __builtin_amdgcn_global_load_lds((const __attribute__((address_space(1))) void*)g,
                                   (__attribute__((address_space(3))) void*)l, 16, 0, 0);
}

DEV void mfma_bf16(f32x4& c, frag8 a, frag8 b) {
  asm("v_mfma_f32_16x16x32_bf16 %0, %1, %2, %0" : "+v"(c) : "v"(a), "v"(b));
}

// ---------------------------------------------------------------------------
// PROVEN round-5 kernel (47 us / ~730 TF at these shapes): 128x128 tile,
// BK=64, 4 waves, SINGLE-buffer 32 KiB LDS, 2-barrier K-step, XOR-swizzled
// LDS via pre-swizzled global source, bijective XCD swizzle. Do not touch.
// MODE: 0 = bf16 out
//       3 = scores: e = exp((s + c2[bz*N+gc])*scale), bf16 out, rowsum atomics
//       4 = PV: f32 out = acc/rowsum[row] + biasp[gc]
// ---------------------------------------------------------------------------
template<int MODE>
__global__ __launch_bounds__(256)
void gemm_bt(const unsigned short* __restrict__ A,
             const unsigned short* __restrict__ Bm,
             const float* __restrict__ bias0, const float* __restrict__ bias1,
             float* __restrict__ rowsum,
             void* __restrict__ Cv,
             int N, int K, float scale,
             long sA, long sB, long sC,
             int nx, int ny)
{
  __shared__ unsigned short ldsA[128 * 64];
  __shared__ unsigned short ldsB[128 * 64];

  const int tid  = threadIdx.x;
  const int lane = tid & 63;
  const int wave = tid >> 6;
  const int wm   = wave >> 1;
  const int wn   = wave & 1;

  const unsigned nwg = gridDim.x;
  const unsigned orig = blockIdx.x;
  const unsigned qq = nwg >> 3, rr = nwg & 7;
  const unsigned xcd = orig & 7, jj = orig >> 3;
  const unsigned wg = (xcd < rr ? xcd * (qq + 1) : rr * (qq + 1) + (xcd - rr) * qq) + jj;
  const unsigned bx = wg % (unsigned)nx;
  const unsigned tt = wg / (unsigned)nx;
  const unsigned by = tt % (unsigned)ny;
  const unsigned bz = tt / (unsigned)ny;

  const int bm = (int)by * 128;
  const int bn = (int)bx * 128;

  A  += (size_t)bz * (size_t)sA;
  Bm += (size_t)bz * (size_t)sB;

  const int r8  = lane >> 3;
  const int l8  = lane & 7;
  const int swz = ((l8 ^ r8) << 4);
  const size_t Kb = (size_t)K * 2;

  const char* gA = (const char*)A  + (size_t)(bm + wave * 32 + r8) * Kb + swz;
  const char* gB = (const char*)Bm + (size_t)(bn + wave * 32 + r8) * Kb + swz;
  char* lA = (char*)ldsA + wave * 32 * 128;
  char* lB = (char*)ldsB + wave * 32 * 128;

  const int cr = lane & 15;
  const int kq = lane >> 4;
  const int base16 = ((kq ^ (cr & 7)) << 4);
  const char* rowA = (const char*)ldsA + (wm * 64 + cr) * 128;
  const char* rowB = (const char*)ldsB + (wn * 64 + cr) * 128;

  f32x4 acc[4][4];
  #pragma unroll
  for (int m = 0; m < 4; ++m)
    #pragma unroll
    for (int n = 0; n < 4; ++n)
      acc[m][n] = f32x4{0.f, 0.f, 0.f, 0.f};

  const int nk = K >> 6;
  for (int kt = 0; kt < nk; ++kt) {
    __syncthreads();
    {
      const char* ga = gA + (size_t)kt * 128;
      const char* gb = gB + (size_t)kt * 128;
      gload_lds16(ga,           lA);
      gload_lds16(gb,           lB);
      gload_lds16(ga +  8 * Kb, lA + 1024);
      gload_lds16(gb +  8 * Kb, lB + 1024);
      gload_lds16(ga + 16 * Kb, lA + 2048);
      gload_lds16(gb + 16 * Kb, lB + 2048);
      gload_lds16(ga + 24 * Kb, lA + 3072);
      gload_lds16(gb + 24 * Kb, lB + 3072);
    }
    __syncthreads();
    #pragma unroll
    for (int kk = 0; kk < 2; ++kk) {
      const int off = base16 ^ (kk << 6);
      frag8 a[4], b[4];
      #pragma unroll
      for (int f = 0; f < 4; ++f) {
        a[f] = *(const frag8*)(rowA + f * 2048 + off);
        b[f] = *(const frag8*)(rowB + f * 2048 + off);
      }
      #pragma unroll
      for (int m = 0; m < 4; ++m)
        #pragma unroll
        for (int n = 0; n < 4; ++n)
          mfma_bf16(acc[m][n], a[m], b[n]);
    }
  }

  #pragma unroll
  for (int m = 0; m < 4; ++m) {
    const int gr0 = bm + wm * 64 + m * 16 + kq * 4;
    float psum[4] = {0.f, 0.f, 0.f, 0.f};
    float inv0 = 1.f, inv1 = 1.f, inv2 = 1.f, inv3 = 1.f;
    if constexpr (MODE == 4) {
      const float4 rs = *(const float4*)&bias0[(size_t)bz * 2048 + gr0];
      inv0 = 1.f / rs.x; inv1 = 1.f / rs.y; inv2 = 1.f / rs.z; inv3 = 1.f / rs.w;
    }
    #pragma unroll
    for (int n = 0; n < 4; ++n) {
      const int gc = bn + wn * 64 + n * 16 + cr;
      float v0 = acc[m][n][0], v1 = acc[m][n][1], v2 = acc[m][n][2], v3 = acc[m][n][3];
      if constexpr (MODE == 3) {
        const float c2v = bias0[(size_t)bz * (size_t)N + gc];
        unsigned short* C = (unsigned short*)Cv + (size_t)bz * (size_t)sC;
        unsigned short e0 = f2bf(__expf((v0 + c2v) * scale));
        unsigned short e1 = f2bf(__expf((v1 + c2v) * scale));
        unsigned short e2 = f2bf(__expf((v2 + c2v) * scale));
        unsigned short e3 = f2bf(__expf((v3 + c2v) * scale));
        C[(size_t)(gr0 + 0) * N + gc] = e0;
        C[(size_t)(gr0 + 1) * N + gc] = e1;
        C[(size_t)(gr0 + 2) * N + gc] = e2;
        C[(size_t)(gr0 + 3) * N + gc] = e3;
        psum[0] += bf2f(e0); psum[1] += bf2f(e1);
        psum[2] += bf2f(e2); psum[3] += bf2f(e3);
      } else if constexpr (MODE == 4) {
        const float bb = bias1[gc];
        float* C = (float*)Cv + (size_t)bz * (size_t)sC;
        C[(size_t)(gr0 + 0) * N + gc] = v0 * inv0 + bb;
        C[(size_t)(gr0 + 1) * N + gc] = v1 * inv1 + bb;
        C[(size_t)(gr0 + 2) * N + gc] = v2 * inv2 + bb;
        C[(size_t)(gr0 + 3) * N + gc] = v3 * inv3 + bb;
      } else {
        unsigned short* C = (unsigned short*)Cv + (size_t)bz * (size_t)sC;
        C[(size_t)(gr0 + 0) * N + gc] = f2bf(v0);
        C[(size_t)(gr0 + 1) * N + gc] = f2bf(v1);
        C[(size_t)(gr0 + 2) * N + gc] = f2bf(v2);
        C[(size_t)(gr0 + 3) * N + gc] = f2bf(v3);
      }
    }
    if constexpr (MODE == 3) {
      #pragma unroll
      for (int j = 0; j < 4; ++j) {
        float p = psum[j];
        p += __shfl_xor(p, 1);
        p += __shfl_xor(p, 2);
        p += __shfl_xor(p, 4);
        p += __shfl_xor(p, 8);
        if (cr == 0) atomicAdd(&rowsum[(size_t)bz * 2048 + gr0 + j], p);
      }
    }
  }
}

// ---------------------------------------------------------------------------
// gemm_qv: q' = Q @ Tt^T (bz=0), v'T = (V @ Wve^T)^T (bz=1). A operand is
// RAW f32 (Q or V) staged via global_load_lds into an f32 LDS region with the
// XOR involution on 16B chunks (chunk ^ ((row&7)<<1), applied on the global
// source col and on the swizzled read slot). cvt->bf16 happens AFTER ds_read,
// so staging stays fully async (fixes round-6 failure). N=K=1024 fixed.
// ---------------------------------------------------------------------------
__global__ __launch_bounds__(256)
void gemm_qv(const float* __restrict__ Qf, const float* __restrict__ Vf,
             const unsigned short* __restrict__ Bm,   // Tt / (+nW) Wve
             void* __restrict__ Cv, long sB, long sC)
{
  __shared__ float          ldsAf[128 * 64];   // 32 KiB (f32 A tile)
  __shared__ unsigned short ldsB [128 * 64];   // 16 KiB (bf16 B tile)

  const int tid  = threadIdx.x;
  const int lane = tid & 63;
  const int wave = tid >> 6;
  const int wm   = wave >> 1;
  const int wn   = wave & 1;

  const unsigned nwg = gridDim.x;
  const unsigned orig = blockIdx.x;
  const unsigned qq = nwg >> 3, rr = nwg & 7;
  const unsigned xcd = orig & 7, jj = orig >> 3;
  const unsigned wg = (xcd < rr ? xcd * (qq + 1) : rr * (qq + 1) + (xcd - rr) * qq) + jj;
  const unsigned bx = wg & 7;           // nx = 8
  const unsigned tt = wg >> 3;
  const unsigned by = tt & 63;          // ny = 64
  const unsigned bz = tt >> 6;          // 0: q', 1: v'

  const int bm = (int)by * 128;
  const int bn = (int)bx * 128;

  const float* A = (bz == 0) ? Qf : Vf;
  Bm += (size_t)bz * (size_t)sB;

  // ---- B staging (proven bf16 path) ----
  const int r8  = lane >> 3;
  const int l8  = lane & 7;
  const int swzB = ((l8 ^ r8) << 4);
  const char* gB = (const char*)Bm + (size_t)(bn + wave * 32 + r8) * 2048 + swzB;
  char* lB = (char*)ldsB + wave * 32 * 128;

  // ---- A staging (f32): 8 gloads/thread/K-step, 4 rows per wave-instr ----
  const int r4  = lane >> 4;            // row within 4
  const int l16 = lane & 15;            // 16B chunk within 256B row
  const int scE = (l16 ^ (r4 << 1)) << 4;   // pre-swizzled byte col, even i
  const char* gAf = (const char*)(A + (size_t)(bm + wave * 32 + r4) * 1024);
  char* lAf = (char*)ldsAf + wave * 32 * 256;

  // ---- fragment read addresses ----
  const int cr = lane & 15;
  const int kq = lane >> 4;
  const int base16 = ((kq ^ (cr & 7)) << 4);    // B side
  const char* rowB = (const char*)ldsB + (wn * 64 + cr) * 128;

  f32x4 acc[4][4];
  #pragma unroll
  for (int m = 0; m < 4; ++m)
    #pragma unroll
    for (int n = 0; n < 4; ++n)
      acc[m][n] = f32x4{0.f, 0.f, 0.f, 0.f};

  for (int kt = 0; kt < 16; ++kt) {
    __syncthreads();
    {
      const char* gb = gB + (size_t)kt * 128;
      gload_lds16(gb,            lB);
      gload_lds16(gb +  8 * 2048, lB + 1024);
      gload_lds16(gb + 16 * 2048, lB + 2048);
      gload_lds16(gb + 24 * 2048, lB + 3072);
      const char* ga = gAf + (size_t)kt * 256;
      #pragma unroll
      for (int i = 0; i < 8; ++i) {
        // row = wave*32 + i*4 + r4 ; src chunk = l16 ^ ((row&7)<<1)
        gload_lds16(ga + (size_t)i * 4 * 4096 + (scE ^ ((i & 1) << 7)),
                    lAf + i * 1024);
      }
    }
    __syncthreads();
    #pragma unroll
    for (int kk = 0; kk < 2; ++kk) {
      const int offB = base16 ^ (kk << 6);
      frag8 a[4], b[4];
      #pragma unroll
      for (int f = 0; f < 4; ++f) {
        // A: row = wm*64 + f*16 + cr ; slot = ((kk<<2)|kq) ^ (cr&7)
        const int slot = ((kk << 2) | kq) ^ (cr & 7);
        const char* p = (const char*)ldsAf + (wm * 64 + f * 16 + cr) * 256 + slot * 32;
        f32x4 lo = *(const f32x4*)p;
        f32x4 hi = *(const f32x4*)(p + 16);
        frag8 av;
        av[0] = f2bf_hw(lo[0]); av[1] = f2bf_hw(lo[1]);
        av[2] = f2bf_hw(lo[2]); av[3] = f2bf_hw(lo[3]);
        av[4] = f2bf_hw(hi[0]); av[5] = f2bf_hw(hi[1]);
        av[6] = f2bf_hw(hi[2]); av[7] = f2bf_hw(hi[3]);
        a[f] = av;
        b[f] = *(const frag8*)(rowB + f * 2048 + offB);
      }
      #pragma unroll
      for (int m = 0; m < 4; ++m)
        #pragma unroll
        for (int n = 0; n < 4; ++n)
          mfma_bf16(acc[m][n], a[m], b[n]);
    }
  }

  // ---- epilogue: MODE-5 semantics (bz0 plain bf16, bz1 transposed) ----
  #pragma unroll
  for (int m = 0; m < 4; ++m) {
    const int gr0 = bm + wm * 64 + m * 16 + kq * 4;
    #pragma unroll
    for (int n = 0; n < 4; ++n) {
      const int gc = bn + wn * 64 + n * 16 + cr;
      float v0 = acc[m][n][0], v1 = acc[m][n][1], v2 = acc[m][n][2], v3 = acc[m][n][3];
      if (bz == 1) {
        unsigned short* C = (unsigned short*)Cv + (size_t)sC;
        ushort4v u;
        u[0] = f2bf(v0); u[1] = f2bf(v1); u[2] = f2bf(v2); u[3] = f2bf(v3);
        *(ushort4v*)&C[((size_t)(gr0 >> 11) << 21) + (size_t)gc * 2048 + (gr0 & 2047)] = u;
      } else {
        unsigned short* C = (unsigned short*)Cv;
        C[(size_t)(gr0 + 0) * 1024 + gc] = f2bf(v0);
        C[(size_t)(gr0 + 1) * 1024 + gc] = f2bf(v1);
        C[(size_t)(gr0 + 2) * 1024 + gc] = f2bf(v2);
        C[(size_t)(gr0 + 3) * 1024 + gc] = f2bf(v3);
      }
    }
  }
}

// ---------------------------------------------------------------------------
// front: ALL independent prep in one dispatch (blocks overlap on the machine)
//  [0,768)      : transpose WQ/WK/WV f32 -> bf16 (WQt/WKt/WVt)
//  [768,1792)   : Weff row + fused biasp
//  [1792,1808)  : u2 partials u2p[mc][k] (no atomics, no zero needed)
//  [1808,1812)  : zero rowsum[8192]
//  [1812,2324)  : cvt K f32 -> bf16 (grid-stride, 512 blocks)
// ---------------------------------------------------------------------------
__global__ __launch_bounds__(256)
void front_kernel(const float* __restrict__ WQ, const float* __restrict__ WK,
                  const float* __restrict__ WV, const float* __restrict__ Wl,
                  const float* __restrict__ Kf,
                  const float* __restrict__ bQ, const float* __restrict__ bV,
                  const float* __restrict__ bl,
                  unsigned short* __restrict__ Wr,
                  unsigned short* __restrict__ Kb,
                  float* __restrict__ u2p, float* __restrict__ biasp,
                  float* __restrict__ rowsum)
{
  __shared__ float t[64][65];
  const int blk = blockIdx.x;
  const int tid = threadIdx.x;

  if (blk < 768) {
    const int z = blk >> 8;
    const int local = blk & 255;
    const float* src = (z == 0) ? WQ : (z == 1) ? WK : WV;
    unsigned short* dst = Wr + (size_t)((z == 0) ? 2 : (z == 1) ? 0 : 3) * 1024 * 1024;
    const int bx  = local & 15;
    const int byy = local >> 4;
    const int tx  = tid & 63;
    const int ty4 = tid >> 6;
    #pragma unroll
    for (int i = 0; i < 16; ++i) {
      const int r = i * 4 + ty4;
      t[r][tx] = src[(size_t)(byy * 64 + r) * 1024 + bx * 64 + tx];
    }
    __syncthreads();
    #pragma unroll
    for (int i = 0; i < 16; ++i) {
      const int r = i * 4 + ty4;
      dst[(size_t)(bx * 64 + r) * 1024 + byy * 64 + tx] = f2bf(t[tx][r]);
    }
  } else if (blk < 1792) {
    const int j = blk - 768;
    const int d = tid * 4;
    float4 s = make_float4(0.f, 0.f, 0.f, 0.f);
    #pragma unroll
    for (int h = 0; h < 8; ++h) {
      float4 w = *(const float4*)&Wl[(size_t)j * 8192 + h * 1024 + d];
      s.x += w.x; s.y += w.y; s.z += w.z; s.w += w.w;
    }
    unsigned short* Weffb = Wr + (size_t)1024 * 1024;
    ushort4v o;
    o[0] = f2bf(s.x); o[1] = f2bf(s.y); o[2] = f2bf(s.z); o[3] = f2bf(s.w);
    *(ushort4v*)&Weffb[(size_t)j * 1024 + d] = o;
    const float4 bv = *(const float4*)&bV[d];
    float p = s.x * bv.x + s.y * bv.y + s.z * bv.z + s.w * bv.w;
    #pragma unroll
    for (int off = 32; off; off >>= 1) p += __shfl_xor(p, off);
    __shared__ float red[4];
    if ((tid & 63) == 0) red[tid >> 6] = p;
    __syncthreads();
    if (tid == 0) biasp[j] = red[0] + red[1] + red[2] + red[3] + bl[j];
  } else if (blk < 1808) {
    const int idx = blk - 1792;
    const int kc = idx & 3, mc = idx >> 2;
    const int k = kc * 256 + tid;
    const int m0 = mc * 256;
    float a = 0.f;
    for (int m = m0; m < m0 + 256; ++m)
      a += WK[(size_t)m * 1024 + k] * bQ[m];
    u2p[(size_t)mc * 1024 + k] = a;
  } else if (blk < 1812) {
    const int i = (blk - 1808) * 2048 + tid * 8;
    #pragma unroll
    for (int j = 0; j < 8; ++j) rowsum[i + j] = 0.f;
  } else {
    int i = (blk - 1812) * 256 + tid;
    const int stride = 512 * 256;
    const int n8 = 1048576;               // 8192*1024/8
    for (; i < n8; i += stride) {
      const float4* p = (const float4*)Kf + (size_t)i * 2;
      float4 a = p[0], b = p[1];
      ushort8 o;
      o[0] = f2bf(a.x); o[1] = f2bf(a.y); o[2] = f2bf(a.z); o[3] = f2bf(a.w);
      o[4] = f2bf(b.x); o[5] = f2bf(b.y); o[6] = f2bf(b.z); o[7] = f2bf(b.w);
      *((ushort8*)Kb + i) = o;
    }
  }
}

// c2[r] = Kb[r,:] . (sum of u2 partials)
__global__ __launch_bounds__(256)
void c2_kernel(const unsigned short* __restrict__ Kb, const float* __restrict__ u2p,
               float* __restrict__ c2)
{
  const int lane = threadIdx.x & 63;
  const int w    = threadIdx.x >> 6;
  const int r    = blockIdx.x * 4 + w;
  float us[16];
  #pragma unroll
  for (int j = 0; j < 4; ++j) {
    float4 x = *(const float4*)&u2p[lane * 16 + j * 4];
    us[j*4+0] = x.x; us[j*4+1] = x.y; us[j*4+2] = x.z; us[j*4+3] = x.w;
  }
  #pragma unroll
  for (int pp = 1; pp < 4; ++pp) {
    #pragma unroll
    for (int j = 0; j < 4; ++j) {
      float4 x = *(const float4*)&u2p[pp * 1024 + lane * 16 + j * 4];
      us[j*4+0] += x.x; us[j*4+1] += x.y; us[j*4+2] += x.z; us[j*4+3] += x.w;
    }
  }
  const unsigned short* kr = Kb + (size_t)r * 1024 + lane * 16;
  ushort8 a = *(const ushort8*)kr;
  ushort8 b = *(const ushort8*)(kr + 8);
  float s = 0.f;
  #pragma unroll
  for (int i = 0; i < 8; ++i) s += bf2f(a[i]) * us[i];
  #pragma unroll
  for (int i = 0; i < 8; ++i) s += bf2f(b[i]) * us[8 + i];
  #pragma unroll
  for (int off = 32; off; off >>= 1) s += __shfl_xor(s, off);
  if (lane == 0) c2[r] = s;
}

// ---------------------------------------------------------------------------
extern "C" void kernel_launch(void* const* d_in, const int* in_sizes, int n_in,
                              void* d_out, int out_size, void* d_ws, size_t ws_size,
                              hipStream_t stream)
{
  (void)in_sizes; (void)n_in; (void)out_size; (void)ws_size;

  const float* Q  = (const float*)d_in[0];
  const float* K  = (const float*)d_in[1];
  const float* V  = (const float*)d_in[2];
  const float* WQ = (const float*)d_in[3];
  const float* bQ = (const float*)d_in[4];
  const float* WK = (const float*)d_in[5];
  const float* bK = (const float*)d_in[6];  (void)bK;  // cancels in softmax
  const float* WV = (const float*)d_in[7];
  const float* bV = (const float*)d_in[8];
  const float* Wl = (const float*)d_in[9];
  const float* bl = (const float*)d_in[10];

  const size_t nX = (size_t)8192 * 1024;   // B*S*D
  const size_t nW = (size_t)1024 * 1024;

  // workspace (bf16 elements):
  // [P: 2*nX][Kb][q'][v'T] | weights: [WKt][Weffb][WQt][WVt][Tt][Wve] | f32 vecs
  unsigned short* Pb  = (unsigned short*)d_ws;   // [4][2048][2048]
  unsigned short* Kb  = Pb + 2 * nX;
  unsigned short* qp  = Pb + 3 * nX;       // q' [8192][1024]; v'T at +nX
  unsigned short* Wr  = Pb + 5 * nX;       // weight region base (= WKt)
  unsigned short* WQt = Wr + 2 * nW;
  unsigned short* Tt  = Wr + 4 * nW;
  float* Fv    = (float*)(Wr + 6 * nW);
  float* rowsum = Fv;                      // 8192
  float* u2p    = Fv + 8192;               // 4 x 1024 partials
  float* c2     = Fv + 12288;              // 8192
  float* biasp  = Fv + 20480;              // 1024

  const int thr = 256;

  // 1) all independent prep + K convert, one dispatch
  front_kernel<<<2324, thr, 0, stream>>>(WQ, WK, WV, Wl, K, bQ, bV, bl,
                                         Wr, Kb, u2p, biasp, rowsum);
  // 2) c2 = Kb . u2
  c2_kernel<<<512, thr, 0, stream>>>(Kb, u2p, c2);
  // 3) Tt = WKt @ WQt^T (bz=0), Wve = Weff @ WVt^T (bz=1)
  gemm_bt<0><<<128, thr, 0, stream>>>(
      Wr, WQt, nullptr, nullptr, nullptr, Tt, 1024, 1024, 1.f,
      (long)nW, (long)nW, (long)nW, 8, 8);
  // 4) q' = Q @ Tt^T (bz=0), v'T = (V @ Wve^T)^T (bz=1); A raw f32
  gemm_qv<<<1024, thr, 0, stream>>>(Q, V, Tt, qp, (long)nW, (long)nX);
  // 5) P = exp((q' K^T + c2)/32), rowsum accumulated
  gemm_bt<3><<<1024, thr, 0, stream>>>(
      qp, Kb, c2, nullptr, rowsum, Pb, 2048, 1024, 0.03125f,
      (long)(2048 * 1024), (long)(2048 * 1024), (long)(2048 * 2048), 16, 16);
  // 6) out = (P @ v'T^T)/rowsum + biasp -> f32
  gemm_bt<4><<<512, thr, 0, stream>>>(
      Pb, qp + nX, rowsum, biasp, nullptr, d_out, 1024, 2048, 1.f,
      (long)(2048 * 2048), (long)(1024 * 2048), (long)(2048 * 1024), 8, 16);
}

// Round 9
// 185.547 us; speedup vs baseline: 1.1555x; 1.0862x over previous
//
#include <hip/hip_runtime.h>
#include <stdint.h>

#define DEV __device__ __forceinline__

typedef __attribute__((ext_vector_type(8))) unsigned short frag8;    // 8 bf16 = 4 VGPR
typedef __attribute__((ext_vector_type(4))) float f32x4;
typedef __attribute__((ext_vector_type(8))) unsigned short ushort8;
typedef __attribute__((ext_vector_type(4))) unsigned short ushort4v;

DEV unsigned short f2bf(float f) {
  union { float f; unsigned u; } x; x.f = f;
  unsigned r = x.u + 0x7fffu + ((x.u >> 16) & 1u);   // RNE
  return (unsigned short)(r >> 16);
}
DEV float bf2f(unsigned short b) {
  union { unsigned u; float f; } x; x.u = ((unsigned)b) << 16;
  return x.f;
}

DEV void gload_lds16(const void* g, void* l) {
  __builtin_amdgcn_global_load_lds((const __attribute__((address_space(1))) void*)g,
                                   (__attribute__((address_space(3))) void*)l, 16, 0, 0);
}

DEV void mfma_bf16(f32x4& c, frag8 a, frag8 b) {
  asm("v_mfma_f32_16x16x32_bf16 %0, %1, %2, %0" : "+v"(c) : "v"(a), "v"(b));
}

// ---------------------------------------------------------------------------
// PROVEN kernel (47 us / ~730 TF at these shapes): 128x128 tile, BK=64,
// 4 waves, SINGLE-buffer 32 KiB LDS, 2-barrier K-step, XOR-swizzled LDS via
// pre-swizzled global source, bijective XCD swizzle. Do not touch.
// MODE: 0 = bf16 out
//       3 = scores: e = exp((s + c2[bz*N+gc])*scale), bf16 out, rowsum atomics
//       4 = PV: f32 out = acc/rowsum[row] + biasp[gc]
//       5 = fused q'/v': bz==0 plain bf16; bz==1 per-batch transposed store
// ---------------------------------------------------------------------------
template<int MODE>
__global__ __launch_bounds__(256)
void gemm_bt(const unsigned short* __restrict__ A,
             const unsigned short* __restrict__ Bm,
             const float* __restrict__ bias0, const float* __restrict__ bias1,
             float* __restrict__ rowsum,
             void* __restrict__ Cv,
             int N, int K, float scale,
             long sA, long sB, long sC,
             int nx, int ny)
{
  __shared__ unsigned short ldsA[128 * 64];
  __shared__ unsigned short ldsB[128 * 64];

  const int tid  = threadIdx.x;
  const int lane = tid & 63;
  const int wave = tid >> 6;
  const int wm   = wave >> 1;
  const int wn   = wave & 1;

  const unsigned nwg = gridDim.x;
  const unsigned orig = blockIdx.x;
  const unsigned qq = nwg >> 3, rr = nwg & 7;
  const unsigned xcd = orig & 7, jj = orig >> 3;
  const unsigned wg = (xcd < rr ? xcd * (qq + 1) : rr * (qq + 1) + (xcd - rr) * qq) + jj;
  const unsigned bx = wg % (unsigned)nx;
  const unsigned tt = wg / (unsigned)nx;
  const unsigned by = tt % (unsigned)ny;
  const unsigned bz = tt / (unsigned)ny;

  const int bm = (int)by * 128;
  const int bn = (int)bx * 128;

  A  += (size_t)bz * (size_t)sA;
  Bm += (size_t)bz * (size_t)sB;

  const int r8  = lane >> 3;
  const int l8  = lane & 7;
  const int swz = ((l8 ^ r8) << 4);
  const size_t Kb = (size_t)K * 2;

  const char* gA = (const char*)A  + (size_t)(bm + wave * 32 + r8) * Kb + swz;
  const char* gB = (const char*)Bm + (size_t)(bn + wave * 32 + r8) * Kb + swz;
  char* lA = (char*)ldsA + wave * 32 * 128;
  char* lB = (char*)ldsB + wave * 32 * 128;

  const int cr = lane & 15;
  const int kq = lane >> 4;
  const int base16 = ((kq ^ (cr & 7)) << 4);
  const char* rowA = (const char*)ldsA + (wm * 64 + cr) * 128;
  const char* rowB = (const char*)ldsB + (wn * 64 + cr) * 128;

  f32x4 acc[4][4];
  #pragma unroll
  for (int m = 0; m < 4; ++m)
    #pragma unroll
    for (int n = 0; n < 4; ++n)
      acc[m][n] = f32x4{0.f, 0.f, 0.f, 0.f};

  const int nk = K >> 6;
  for (int kt = 0; kt < nk; ++kt) {
    __syncthreads();
    {
      const char* ga = gA + (size_t)kt * 128;
      const char* gb = gB + (size_t)kt * 128;
      gload_lds16(ga,           lA);
      gload_lds16(gb,           lB);
      gload_lds16(ga +  8 * Kb, lA + 1024);
      gload_lds16(gb +  8 * Kb, lB + 1024);
      gload_lds16(ga + 16 * Kb, lA + 2048);
      gload_lds16(gb + 16 * Kb, lB + 2048);
      gload_lds16(ga + 24 * Kb, lA + 3072);
      gload_lds16(gb + 24 * Kb, lB + 3072);
    }
    __syncthreads();
    #pragma unroll
    for (int kk = 0; kk < 2; ++kk) {
      const int off = base16 ^ (kk << 6);
      frag8 a[4], b[4];
      #pragma unroll
      for (int f = 0; f < 4; ++f) {
        a[f] = *(const frag8*)(rowA + f * 2048 + off);
        b[f] = *(const frag8*)(rowB + f * 2048 + off);
      }
      #pragma unroll
      for (int m = 0; m < 4; ++m)
        #pragma unroll
        for (int n = 0; n < 4; ++n)
          mfma_bf16(acc[m][n], a[m], b[n]);
    }
  }

  #pragma unroll
  for (int m = 0; m < 4; ++m) {
    const int gr0 = bm + wm * 64 + m * 16 + kq * 4;
    float psum[4] = {0.f, 0.f, 0.f, 0.f};
    float inv0 = 1.f, inv1 = 1.f, inv2 = 1.f, inv3 = 1.f;
    if constexpr (MODE == 4) {
      const float4 rs = *(const float4*)&bias0[(size_t)bz * 2048 + gr0];
      inv0 = 1.f / rs.x; inv1 = 1.f / rs.y; inv2 = 1.f / rs.z; inv3 = 1.f / rs.w;
    }
    #pragma unroll
    for (int n = 0; n < 4; ++n) {
      const int gc = bn + wn * 64 + n * 16 + cr;
      float v0 = acc[m][n][0], v1 = acc[m][n][1], v2 = acc[m][n][2], v3 = acc[m][n][3];
      if constexpr (MODE == 3) {
        const float c2v = bias0[(size_t)bz * (size_t)N + gc];
        unsigned short* C = (unsigned short*)Cv + (size_t)bz * (size_t)sC;
        unsigned short e0 = f2bf(__expf((v0 + c2v) * scale));
        unsigned short e1 = f2bf(__expf((v1 + c2v) * scale));
        unsigned short e2 = f2bf(__expf((v2 + c2v) * scale));
        unsigned short e3 = f2bf(__expf((v3 + c2v) * scale));
        C[(size_t)(gr0 + 0) * N + gc] = e0;
        C[(size_t)(gr0 + 1) * N + gc] = e1;
        C[(size_t)(gr0 + 2) * N + gc] = e2;
        C[(size_t)(gr0 + 3) * N + gc] = e3;
        psum[0] += bf2f(e0); psum[1] += bf2f(e1);
        psum[2] += bf2f(e2); psum[3] += bf2f(e3);
      } else if constexpr (MODE == 4) {
        const float bb = bias1[gc];
        float* C = (float*)Cv + (size_t)bz * (size_t)sC;
        C[(size_t)(gr0 + 0) * N + gc] = v0 * inv0 + bb;
        C[(size_t)(gr0 + 1) * N + gc] = v1 * inv1 + bb;
        C[(size_t)(gr0 + 2) * N + gc] = v2 * inv2 + bb;
        C[(size_t)(gr0 + 3) * N + gc] = v3 * inv3 + bb;
      } else if constexpr (MODE == 5) {
        if (bz == 1) {
          // transposed store: v'T[b][d][s], b = gr0>>11, s = gr0&2047, d = gc
          unsigned short* C = (unsigned short*)Cv + (size_t)sC;
          ushort4v u;
          u[0] = f2bf(v0); u[1] = f2bf(v1); u[2] = f2bf(v2); u[3] = f2bf(v3);
          *(ushort4v*)&C[((size_t)(gr0 >> 11) << 21) + (size_t)gc * 2048 + (gr0 & 2047)] = u;
        } else {
          unsigned short* C = (unsigned short*)Cv;
          C[(size_t)(gr0 + 0) * N + gc] = f2bf(v0);
          C[(size_t)(gr0 + 1) * N + gc] = f2bf(v1);
          C[(size_t)(gr0 + 2) * N + gc] = f2bf(v2);
          C[(size_t)(gr0 + 3) * N + gc] = f2bf(v3);
        }
      } else {
        unsigned short* C = (unsigned short*)Cv + (size_t)bz * (size_t)sC;
        C[(size_t)(gr0 + 0) * N + gc] = f2bf(v0);
        C[(size_t)(gr0 + 1) * N + gc] = f2bf(v1);
        C[(size_t)(gr0 + 2) * N + gc] = f2bf(v2);
        C[(size_t)(gr0 + 3) * N + gc] = f2bf(v3);
      }
    }
    if constexpr (MODE == 3) {
      #pragma unroll
      for (int j = 0; j < 4; ++j) {
        float p = psum[j];
        p += __shfl_xor(p, 1);
        p += __shfl_xor(p, 2);
        p += __shfl_xor(p, 4);
        p += __shfl_xor(p, 8);
        if (cr == 0) atomicAdd(&rowsum[(size_t)bz * 2048 + gr0 + j], p);
      }
    }
  }
}

// ---------------------------------------------------------------------------
// front: ALL independent prep in one dispatch (blocks overlap on the machine)
//  [0,768)      : transpose WQ/WK/WV f32 -> bf16 (WQt/WKt/WVt)
//  [768,1792)   : Weff row + fused biasp
//  [1792,1808)  : u2 partials u2p[mc][k] (no atomics, no zero needed)
//  [1808,1812)  : zero rowsum[8192]
//  [1812,3348)  : cvt Q/V/K f32 -> bf16 (512 grid-stride blocks per tensor;
//                 dst = Xb + z*nX since Qb,Vb,Kb are contiguous)
// ---------------------------------------------------------------------------
__global__ __launch_bounds__(256)
void front_kernel(const float* __restrict__ WQ, const float* __restrict__ WK,
                  const float* __restrict__ WV, const float* __restrict__ Wl,
                  const float* __restrict__ Qf, const float* __restrict__ Vf,
                  const float* __restrict__ Kf,
                  const float* __restrict__ bQ, const float* __restrict__ bV,
                  const float* __restrict__ bl,
                  unsigned short* __restrict__ Wr,
                  unsigned short* __restrict__ Xb,
                  float* __restrict__ u2p, float* __restrict__ biasp,
                  float* __restrict__ rowsum)
{
  __shared__ float t[64][65];
  const int blk = blockIdx.x;
  const int tid = threadIdx.x;

  if (blk < 768) {
    const int z = blk >> 8;
    const int local = blk & 255;
    const float* src = (z == 0) ? WQ : (z == 1) ? WK : WV;
    unsigned short* dst = Wr + (size_t)((z == 0) ? 2 : (z == 1) ? 0 : 3) * 1024 * 1024;
    const int bx  = local & 15;
    const int byy = local >> 4;
    const int tx  = tid & 63;
    const int ty4 = tid >> 6;
    #pragma unroll
    for (int i = 0; i < 16; ++i) {
      const int r = i * 4 + ty4;
      t[r][tx] = src[(size_t)(byy * 64 + r) * 1024 + bx * 64 + tx];
    }
    __syncthreads();
    #pragma unroll
    for (int i = 0; i < 16; ++i) {
      const int r = i * 4 + ty4;
      dst[(size_t)(bx * 64 + r) * 1024 + byy * 64 + tx] = f2bf(t[tx][r]);
    }
  } else if (blk < 1792) {
    const int j = blk - 768;
    const int d = tid * 4;
    float4 s = make_float4(0.f, 0.f, 0.f, 0.f);
    #pragma unroll
    for (int h = 0; h < 8; ++h) {
      float4 w = *(const float4*)&Wl[(size_t)j * 8192 + h * 1024 + d];
      s.x += w.x; s.y += w.y; s.z += w.z; s.w += w.w;
    }
    unsigned short* Weffb = Wr + (size_t)1024 * 1024;
    ushort4v o;
    o[0] = f2bf(s.x); o[1] = f2bf(s.y); o[2] = f2bf(s.z); o[3] = f2bf(s.w);
    *(ushort4v*)&Weffb[(size_t)j * 1024 + d] = o;
    const float4 bv = *(const float4*)&bV[d];
    float p = s.x * bv.x + s.y * bv.y + s.z * bv.z + s.w * bv.w;
    #pragma unroll
    for (int off = 32; off; off >>= 1) p += __shfl_xor(p, off);
    __shared__ float red[4];
    if ((tid & 63) == 0) red[tid >> 6] = p;
    __syncthreads();
    if (tid == 0) biasp[j] = red[0] + red[1] + red[2] + red[3] + bl[j];
  } else if (blk < 1808) {
    const int idx = blk - 1792;
    const int kc = idx & 3, mc = idx >> 2;
    const int k = kc * 256 + tid;
    const int m0 = mc * 256;
    float a = 0.f;
    for (int m = m0; m < m0 + 256; ++m)
      a += WK[(size_t)m * 1024 + k] * bQ[m];
    u2p[(size_t)mc * 1024 + k] = a;
  } else if (blk < 1812) {
    const int i = (blk - 1808) * 2048 + tid * 8;
    #pragma unroll
    for (int j = 0; j < 8; ++j) rowsum[i + j] = 0.f;
  } else {
    const int local = blk - 1812;             // 0..1535
    const int z = local >> 9;                 // 0:Q 1:V 2:K
    const float* src = (z == 0) ? Qf : (z == 1) ? Vf : Kf;
    unsigned short* dst = Xb + (size_t)z * (size_t)8192 * 1024;
    int i = (local & 511) * 256 + tid;
    const int n8 = 1048576;                   // 8192*1024/8
    for (; i < n8; i += 512 * 256) {
      const float4* p = (const float4*)src + (size_t)i * 2;
      float4 a = p[0], b = p[1];
      ushort8 o;
      o[0] = f2bf(a.x); o[1] = f2bf(a.y); o[2] = f2bf(a.z); o[3] = f2bf(a.w);
      o[4] = f2bf(b.x); o[5] = f2bf(b.y); o[6] = f2bf(b.z); o[7] = f2bf(b.w);
      *((ushort8*)dst + i) = o;
    }
  }
}

// c2[r] = Kb[r,:] . (sum of u2 partials)
__global__ __launch_bounds__(256)
void c2_kernel(const unsigned short* __restrict__ Kb, const float* __restrict__ u2p,
               float* __restrict__ c2)
{
  const int lane = threadIdx.x & 63;
  const int w    = threadIdx.x >> 6;
  const int r    = blockIdx.x * 4 + w;
  float us[16];
  #pragma unroll
  for (int j = 0; j < 4; ++j) {
    float4 x = *(const float4*)&u2p[lane * 16 + j * 4];
    us[j*4+0] = x.x; us[j*4+1] = x.y; us[j*4+2] = x.z; us[j*4+3] = x.w;
  }
  #pragma unroll
  for (int pp = 1; pp < 4; ++pp) {
    #pragma unroll
    for (int j = 0; j < 4; ++j) {
      float4 x = *(const float4*)&u2p[pp * 1024 + lane * 16 + j * 4];
      us[j*4+0] += x.x; us[j*4+1] += x.y; us[j*4+2] += x.z; us[j*4+3] += x.w;
    }
  }
  const unsigned short* kr = Kb + (size_t)r * 1024 + lane * 16;
  ushort8 a = *(const ushort8*)kr;
  ushort8 b = *(const ushort8*)(kr + 8);
  float s = 0.f;
  #pragma unroll
  for (int i = 0; i < 8; ++i) s += bf2f(a[i]) * us[i];
  #pragma unroll
  for (int i = 0; i < 8; ++i) s += bf2f(b[i]) * us[8 + i];
  #pragma unroll
  for (int off = 32; off; off >>= 1) s += __shfl_xor(s, off);
  if (lane == 0) c2[r] = s;
}

// ---------------------------------------------------------------------------
extern "C" void kernel_launch(void* const* d_in, const int* in_sizes, int n_in,
                              void* d_out, int out_size, void* d_ws, size_t ws_size,
                              hipStream_t stream)
{
  (void)in_sizes; (void)n_in; (void)out_size; (void)ws_size;

  const float* Q  = (const float*)d_in[0];
  const float* K  = (const float*)d_in[1];
  const float* V  = (const float*)d_in[2];
  const float* WQ = (const float*)d_in[3];
  const float* bQ = (const float*)d_in[4];
  const float* WK = (const float*)d_in[5];
  const float* bK = (const float*)d_in[6];  (void)bK;  // cancels in softmax
  const float* WV = (const float*)d_in[7];
  const float* bV = (const float*)d_in[8];
  const float* Wl = (const float*)d_in[9];
  const float* bl = (const float*)d_in[10];

  const size_t nX = (size_t)8192 * 1024;   // B*S*D
  const size_t nW = (size_t)1024 * 1024;

  // workspace (bf16 elements):
  // [Qb][Vb][Kb][q'][v'T] | weights: [WKt][Weffb][WQt][WVt][Tt][Wve] | f32 vecs
  // P ([4][2048][2048] = 2*nX) overlays Qb+Vb after they are consumed.
  unsigned short* Qb  = (unsigned short*)d_ws;
  unsigned short* Kb  = Qb + 2 * nX;
  unsigned short* qp  = Qb + 3 * nX;       // q' [8192][1024]; v'T at +nX
  unsigned short* Wr  = Qb + 5 * nX;       // weight region base (= WKt)
  unsigned short* WQt = Wr + 2 * nW;
  unsigned short* Tt  = Wr + 4 * nW;
  float* Fv    = (float*)(Wr + 6 * nW);
  float* rowsum = Fv;                      // 8192
  float* u2p    = Fv + 8192;               // 4 x 1024 partials
  float* c2     = Fv + 12288;              // 8192
  float* biasp  = Fv + 20480;              // 1024
  unsigned short* Pb = Qb;                 // overlays [0, 2*nX)

  const int thr = 256;

  // 1) all independent prep + Q/V/K converts, one dispatch
  front_kernel<<<3348, thr, 0, stream>>>(WQ, WK, WV, Wl, Q, V, K, bQ, bV, bl,
                                         Wr, Qb, u2p, biasp, rowsum);
  // 2) c2 = Kb . u2
  c2_kernel<<<512, thr, 0, stream>>>(Kb, u2p, c2);
  // 3) Tt = WKt @ WQt^T (bz=0), Wve = Weff @ WVt^T (bz=1)
  gemm_bt<0><<<128, thr, 0, stream>>>(
      Wr, WQt, nullptr, nullptr, nullptr, Tt, 1024, 1024, 1.f,
      (long)nW, (long)nW, (long)nW, 8, 8);
  // 4) q' = Qb @ Tt^T (bz=0), v'T = (Vb @ Wve^T)^T (bz=1)
  gemm_bt<5><<<1024, thr, 0, stream>>>(
      Qb, Tt, nullptr, nullptr, nullptr, qp, 1024, 1024, 1.f,
      (long)nX, (long)nW, (long)nX, 8, 64);
  // 5) P = exp((q' K^T + c2)/32), rowsum accumulated
  gemm_bt<3><<<1024, thr, 0, stream>>>(
      qp, Kb, c2, nullptr, rowsum, Pb, 2048, 1024, 0.03125f,
      (long)(2048 * 1024), (long)(2048 * 1024), (long)(2048 * 2048), 16, 16);
  // 6) out = (P @ v'T^T)/rowsum + biasp -> f32
  gemm_bt<4><<<512, thr, 0, stream>>>(
      Pb, qp + nX, rowsum, biasp, nullptr, d_out, 1024, 2048, 1.f,
      (long)(2048 * 2048), (long)(1024 * 2048), (long)(2048 * 1024), 8, 16);
}